// Round 1
// baseline (449.696 us; speedup 1.0000x reference)
//
#include <hip/hip_runtime.h>
#include <hip/hip_bf16.h>
#include <stdint.h>

#define NTOT 65536   // B * N_NODE
#define NNODE 2048
#define CIN 12

__device__ __forceinline__ float bf2f(uint32_t u) {
    union { uint32_t i; float f; } v; v.i = u << 16; return v.f;
}
__device__ __forceinline__ uint16_t f2bf(float f) {
    union { float f; uint32_t i; } v; v.f = f;
    uint32_t x = v.i;
    uint32_t r = x + 0x7fffu + ((x >> 16) & 1u);
    return (uint16_t)(r >> 16);
}
__device__ __forceinline__ float bflo(uint32_t u) { return bf2f(u & 0xffffu); }
__device__ __forceinline__ float bfhi(uint32_t u) { return bf2f(u >> 16); }
__device__ __forceinline__ float sigmf(float x) {
    return __builtin_amdgcn_rcpf(1.0f + __expf(-x));
}
__device__ __forceinline__ float tanhfast(float x) {
    float ex = __expf(2.0f * x);
    return 1.0f - 2.0f * __builtin_amdgcn_rcpf(ex + 1.0f);
}
__device__ __forceinline__ float lrelu(float v) { return v > 0.f ? v : 0.2f * v; }

// ws float offsets (flags[0]=bf16?, flags[1]=edge stride words, flags[2]=gcount)
#define O_WG   16
#define O_AS   1168
#define O_AD   1264
#define O_BIAS 1360
#define O_BIH1 1376
#define O_BHH1 1504
#define O_BIH2 1632
#define O_BHH2 2144
#define O_BLIN 2656
#define O_END  21088

__device__ __forceinline__ void cvt(const void* s, float* d, int i, int bf) {
    d[i] = bf ? bf2f(((const uint16_t*)s)[i]) : ((const float*)s)[i];
}

// ---------- fused: dtype detect + small-tensor conv + zero ----------
__global__ void __launch_bounds__(256) k_pre(
    const void* x, const int* __restrict__ e32,
    const void* wg, const void* as_, const void* ad_, const void* bs,
    const void* b1, const void* bb1, const void* b2, const void* bb2,
    const void* bl, float* __restrict__ ws, int* __restrict__ deg) {
    int tid = threadIdx.x, lane = tid & 63;
    uint32_t u = ((const uint16_t*)x)[2 * lane];
    uint32_t ex = (u >> 7) & 0xFF;
    bool sane = (ex >= 0x60 && ex <= 0x9F) || (u == 0);
    unsigned long long bsx = __ballot(sane);
    bool hi_zero = (e32[2 * lane + 1] == 0);
    unsigned long long bz = __ballot(hi_zero);
    int bf = (__popcll(bsx) >= 52) ? 1 : 0;
    int st = (__popcll(bz) == 64) ? 2 : 1;
    if (blockIdx.x == 0 && tid == 0) {
        ((int*)ws)[0] = bf; ((int*)ws)[1] = st; ((int*)ws)[2] = 0;
    }
    deg[blockIdx.x * 256 + tid] = 0;
    int i = blockIdx.x * 256 + tid;
    if (i < 1152)  { cvt(wg,  ws + O_WG,   i, bf); return; } i -= 1152;
    if (i < 96)    { cvt(as_, ws + O_AS,   i, bf); return; } i -= 96;
    if (i < 96)    { cvt(ad_, ws + O_AD,   i, bf); return; } i -= 96;
    if (i < 12)    { cvt(bs,  ws + O_BIAS, i, bf); return; } i -= 12;
    if (i < 128)   { cvt(b1,  ws + O_BIH1, i, bf); return; } i -= 128;
    if (i < 128)   { cvt(bb1, ws + O_BHH1, i, bf); return; } i -= 128;
    if (i < 512)   { cvt(b2,  ws + O_BIH2, i, bf); return; } i -= 512;
    if (i < 512)   { cvt(bb2, ws + O_BHH2, i, bf); return; } i -= 512;
    if (i < 18432) { cvt(bl,  ws + O_BLIN, i, bf); }
}

// ---------- fused attention scores + edge histogram ----------
__global__ void __launch_bounds__(256) k_nfa(const void* __restrict__ xraw,
                                             const float* __restrict__ Wg,
                                             const float* __restrict__ att,
                                             const int* __restrict__ flags,
                                             const int* __restrict__ e, int E,
                                             int* __restrict__ deg, int* __restrict__ rank,
                                             float* __restrict__ a_s, float* __restrict__ a_d) {
    __shared__ float sx[384];
    __shared__ float sw[1152];
    __shared__ float satt[192];
    __shared__ float sh[3072];
    int tid = threadIdx.x;
    int n0 = blockIdx.x * 32;
    if (flags[0]) {
        const uint32_t* xp = (const uint32_t*)xraw;
        for (int i = tid; i < 192; i += 256) {
            uint32_t u = xp[n0 * 6 + i];
            sx[2 * i] = bflo(u); sx[2 * i + 1] = bfhi(u);
        }
    } else {
        const float* xp = (const float*)xraw;
        for (int i = tid; i < 384; i += 256) sx[i] = xp[n0 * 12 + i];
    }
    for (int i = tid; i < 1152; i += 256) sw[i] = Wg[i];
    if (tid < 192) satt[tid] = att[tid];
    {
        long st = flags[1];
        int chunk = (E + gridDim.x - 1) / gridDim.x;
        int ebase = blockIdx.x * chunk;
        int eend = min(ebase + chunk, E);
        for (int i = ebase + tid; i < eend; i += 256) {
            int d = e[st * (E + i)];
            rank[i] = atomicAdd(&deg[d], 1);
        }
    }
    __syncthreads();
#pragma unroll
    for (int r = 0; r < 12; r++) {
        int idx = r * 256 + tid;
        int n = idx / 96, o = idx % 96;
        float acc = 0.f;
#pragma unroll
        for (int k = 0; k < 12; k++) acc += sx[n * 12 + k] * sw[k * 96 + o];
        sh[idx] = acc;
    }
    __syncthreads();
    {
        int nl = tid >> 3, h = tid & 7;
        const float* hr = sh + nl * 96 + h * 12;
        float s = 0.f, dd = 0.f;
#pragma unroll
        for (int c = 0; c < 12; c++) {
            float v = hr[c];
            s += v * satt[h * 12 + c];
            dd += v * satt[96 + h * 12 + c];
        }
        a_s[n0 * 8 + tid] = s;
        a_d[n0 * 8 + tid] = dd;
    }
}

// ---------- scan: local exclusive scan + atomic global base ----------
__global__ void k_scan(const int* __restrict__ deg, int* __restrict__ offs,
                       int* __restrict__ gcount) {
    __shared__ int s[256];
    __shared__ int base;
    int t = threadIdx.x, i = blockIdx.x * 256 + t;
    int v = deg[i];
    s[t] = v; __syncthreads();
    for (int off = 1; off < 256; off <<= 1) {
        int a = (t >= off) ? s[t - off] : 0;
        __syncthreads();
        s[t] += a;
        __syncthreads();
    }
    if (t == 255) base = atomicAdd(gcount, s[255]);
    __syncthreads();
    offs[i] = base + s[t] - v;
}

__global__ void k_scatter(const int* __restrict__ e, int E, const int* __restrict__ flags,
                          const int* __restrict__ offs, const int* __restrict__ rank,
                          int* __restrict__ ssrc) {
    int i = blockIdx.x * 256 + threadIdx.x;
    if (i < E) {
        long st = flags[1];
        int s = e[st * i];
        int d = e[st * (E + i)];
        ssrc[offs[d] + rank[i]] = s;
    }
}

// ---------- GAT aggregation: aggregate x (12ch), project through Wg per node ----------
__global__ void __launch_bounds__(256) k_agg(
    const void* __restrict__ xraw, const float* __restrict__ WgG,
    const float* __restrict__ a_s, const float* __restrict__ a_d,
    const int* __restrict__ offs, const int* __restrict__ deg,
    const int* __restrict__ ssrc, const float* __restrict__ bias,
    const int* __restrict__ flags, float* __restrict__ gT) {
    __shared__ float swg[1152];
    __shared__ float sres[4][12];
    int tid = threadIdx.x, wave = tid >> 6, lane = tid & 63;
    for (int i = tid; i < 1152; i += 256) swg[i] = WgG[i];
    __syncthreads();
    int node = blockIdx.x * 4 + wave;
    int beg = offs[node], d = deg[node];
    int sub = lane >> 3, h = lane & 7;
    float adh = a_d[node * 8 + h];
    int bf = flags[0];
    float acc[12];
    float wsum = 0.f;
#pragma unroll
    for (int c = 0; c < 12; c++) acc[c] = 0.f;
    if (sub == 0) {
        float w = __expf(lrelu(a_s[node * 8 + h] + adh));
        wsum = w;
        if (bf) {
            const uint2* xp = (const uint2*)((const uint16_t*)xraw + node * 12);
            uint2 u0 = xp[0], u1 = xp[1], u2 = xp[2];
            acc[0] = w * bflo(u0.x); acc[1] = w * bfhi(u0.x);
            acc[2] = w * bflo(u0.y); acc[3] = w * bfhi(u0.y);
            acc[4] = w * bflo(u1.x); acc[5] = w * bfhi(u1.x);
            acc[6] = w * bflo(u1.y); acc[7] = w * bfhi(u1.y);
            acc[8] = w * bflo(u2.x); acc[9] = w * bfhi(u2.x);
            acc[10] = w * bflo(u2.y); acc[11] = w * bfhi(u2.y);
        } else {
            const float4* xp = (const float4*)((const float*)xraw + node * 12);
            float4 v0 = xp[0], v1 = xp[1], v2 = xp[2];
            acc[0] = w * v0.x; acc[1] = w * v0.y; acc[2] = w * v0.z; acc[3] = w * v0.w;
            acc[4] = w * v1.x; acc[5] = w * v1.y; acc[6] = w * v1.z; acc[7] = w * v1.w;
            acc[8] = w * v2.x; acc[9] = w * v2.y; acc[10] = w * v2.z; acc[11] = w * v2.w;
        }
    }
    for (int base = 0; base < d; base += 8) {
        int k = base + sub;
        if (k < d) {
            int s = ssrc[beg + k];
            float w = __expf(lrelu(a_s[s * 8 + h] + adh));
            wsum += w;
            if (bf) {
                const uint2* xp = (const uint2*)((const uint16_t*)xraw + s * 12);
                uint2 u0 = xp[0], u1 = xp[1], u2 = xp[2];
                acc[0] += w * bflo(u0.x); acc[1] += w * bfhi(u0.x);
                acc[2] += w * bflo(u0.y); acc[3] += w * bfhi(u0.y);
                acc[4] += w * bflo(u1.x); acc[5] += w * bfhi(u1.x);
                acc[6] += w * bflo(u1.y); acc[7] += w * bfhi(u1.y);
                acc[8] += w * bflo(u2.x); acc[9] += w * bfhi(u2.x);
                acc[10] += w * bflo(u2.y); acc[11] += w * bfhi(u2.y);
            } else {
                const float4* xp = (const float4*)((const float*)xraw + s * 12);
                float4 v0 = xp[0], v1 = xp[1], v2 = xp[2];
                acc[0] += w * v0.x; acc[1] += w * v0.y; acc[2] += w * v0.z; acc[3] += w * v0.w;
                acc[4] += w * v1.x; acc[5] += w * v1.y; acc[6] += w * v1.z; acc[7] += w * v1.w;
                acc[8] += w * v2.x; acc[9] += w * v2.y; acc[10] += w * v2.z; acc[11] += w * v2.w;
            }
        }
    }
#pragma unroll
    for (int off = 8; off <= 32; off <<= 1) {
        wsum += __shfl_xor(wsum, off, 64);
#pragma unroll
        for (int c = 0; c < 12; c++) acc[c] += __shfl_xor(acc[c], off, 64);
    }
    float invw = 1.f / wsum;
#pragma unroll
    for (int c = 0; c < 12; c++) acc[c] *= invw;
    float p0 = 0.f, p1 = 0.f;
    const float* wcol = swg + h * 12;
#pragma unroll
    for (int k = 0; k < 12; k++) {
        float a = acc[k];
        p0 += a * wcol[k * 96 + sub];
        p1 += a * wcol[k * 96 + sub + 4];
    }
#pragma unroll
    for (int off = 1; off <= 4; off <<= 1) {
        p0 += __shfl_xor(p0, off, 64);
        p1 += __shfl_xor(p1, off, 64);
    }
    if (h == 0) {
        sres[wave][sub] = p0;
        if (sub >= 4) sres[wave][sub + 4] = p1;
    }
    __syncthreads();
    if (tid < 48) {
        int no = tid / 12, c = tid % 12;
        gT[c * NTOT + blockIdx.x * 4 + no] = sres[no][c] * 0.125f + bias[c];
    }
}

// ---------- Z1: 4 batches per block, weight loads shared ----------
__global__ void __launch_bounds__(256) k_z1(const float* __restrict__ gT,
                                            const void* __restrict__ Wraw,
                                            const float* __restrict__ b1,
                                            const float* __restrict__ b2,
                                            const int* __restrict__ flags,
                                            float* __restrict__ Z1) {
    int t = blockIdx.x >> 3, bg = (blockIdx.x & 7) * 4;
    __shared__ float sv[4][2048];
    __shared__ float zp[2][4][128];
    int tid = threadIdx.x;
#pragma unroll
    for (int q = 0; q < 4; q++)
        for (int v = tid; v < 2048; v += 256) sv[q][v] = gT[t * NTOT + (bg + q) * NNODE + v];
    __syncthreads();
    int row = tid & 127, half = tid >> 7;
    float a0 = 0.f, a1 = 0.f, a2 = 0.f, a3 = 0.f;
    int hbase = half * 1024;
    if (flags[0]) {
        const uint4* wp = (const uint4*)((const uint16_t*)Wraw + row * 2048 + hbase);
        for (int k = 0; k < 128; k++) {
            uint4 u = wp[k];
            float w0 = bflo(u.x), w1 = bfhi(u.x), w2 = bflo(u.y), w3 = bfhi(u.y);
            float w4 = bflo(u.z), w5 = bfhi(u.z), w6 = bflo(u.w), w7 = bfhi(u.w);
#pragma unroll
            for (int q = 0; q < 4; q++) {
                float4 A = *(const float4*)&sv[q][hbase + 8 * k];
                float4 B = *(const float4*)&sv[q][hbase + 8 * k + 4];
                float r = w0 * A.x + w1 * A.y + w2 * A.z + w3 * A.w
                        + w4 * B.x + w5 * B.y + w6 * B.z + w7 * B.w;
                if (q == 0) a0 += r; else if (q == 1) a1 += r;
                else if (q == 2) a2 += r; else a3 += r;
            }
        }
    } else {
        const float4* wp = (const float4*)((const float*)Wraw + row * 2048 + hbase);
        for (int k = 0; k < 256; k++) {
            float4 w = wp[k];
#pragma unroll
            for (int q = 0; q < 4; q++) {
                float4 A = *(const float4*)&sv[q][hbase + 4 * k];
                float r = w.x * A.x + w.y * A.y + w.z * A.z + w.w * A.w;
                if (q == 0) a0 += r; else if (q == 1) a1 += r;
                else if (q == 2) a2 += r; else a3 += r;
            }
        }
    }
    zp[half][0][row] = a0; zp[half][1][row] = a1;
    zp[half][2][row] = a2; zp[half][3][row] = a3;
    __syncthreads();
    if (tid < 128) {
        float bb = b1[tid] + b2[tid];
#pragma unroll
        for (int q = 0; q < 4; q++)
            Z1[t * 4096 + (bg + q) * 128 + tid] = zp[0][q][tid] + zp[1][q][tid] + bb;
    }
}

// ---------- fused tail: LSTM1 + Wih2 proj + LSTM2 ----------
// Redesigned: 256 threads = 4 waves. Thread layout for LSTM2:
//   lane bit5 = qh (K-half 0/1, and zin gate-pair owner), e = wave*32 + (lane&31).
//   Each thread computes 4 gate PARTIALS for element e over its 64-wide K-half
//   with the 4x64 bf16 weight slice pinned in VGPRs; partials completed by one
//   shfl_xor(32). One barrier per step via double-buffered hb. zs2 eliminated:
//   Phase C computes zin(gates 2qh,2qh+1) into registers of the consuming thread.
__global__ void __launch_bounds__(256, 1) k_tail(
    const float* __restrict__ Z1,
    const void* __restrict__ Whh1r,
    const void* __restrict__ Wih2r, const void* __restrict__ Whh2r,
    const float* __restrict__ b2i, const float* __restrict__ b2h,
    const int* __restrict__ flags, float* __restrict__ h2l) {
    int b = blockIdx.x, tid = threadIdx.x;
    __shared__ __align__(16) float h1s[12 * 32];
    __shared__ __align__(16) float hb1[32];
    __shared__ __align__(16) float hb[2][128];
    int bf = flags[0];
    int lane = tid & 63, wv = tid >> 6;
    int qh = lane >> 5;             // K-half + zin gate-pair
    int e = wv * 32 + (lane & 31);  // element 0..127

    // ---- prologue: pin LSTM2 weights + Wih2 rows (overlaps Phase B) ----
    int rA = e + 256 * qh;          // row of gate 2qh   (i or g)
    int rB = e + 128 + 256 * qh;    // row of gate 2qh+1 (f or o)
    float zbA = b2i[rA] + b2h[rA];
    float zbB = b2i[rB] + b2h[rB];
    float wA_[32], wB_[32];
    uint4 wd[32];
    if (bf) {
        const uint16_t* W2 = (const uint16_t*)Whh2r;
#pragma unroll
        for (int q = 0; q < 4; q++) {
            const uint4* p = (const uint4*)(W2 + (q * 128 + e) * 128 + qh * 64);
#pragma unroll
            for (int k = 0; k < 8; k++) wd[q * 8 + k] = p[k];
        }
        const uint4* wiA = (const uint4*)((const uint16_t*)Wih2r + rA * 32);
        const uint4* wiB = (const uint4*)((const uint16_t*)Wih2r + rB * 32);
#pragma unroll
        for (int k = 0; k < 4; k++) {
            uint4 ua = wiA[k], ub = wiB[k];
            wA_[8 * k + 0] = bflo(ua.x); wA_[8 * k + 1] = bfhi(ua.x);
            wA_[8 * k + 2] = bflo(ua.y); wA_[8 * k + 3] = bfhi(ua.y);
            wA_[8 * k + 4] = bflo(ua.z); wA_[8 * k + 5] = bfhi(ua.z);
            wA_[8 * k + 6] = bflo(ua.w); wA_[8 * k + 7] = bfhi(ua.w);
            wB_[8 * k + 0] = bflo(ub.x); wB_[8 * k + 1] = bfhi(ub.x);
            wB_[8 * k + 2] = bflo(ub.y); wB_[8 * k + 3] = bfhi(ub.y);
            wB_[8 * k + 4] = bflo(ub.z); wB_[8 * k + 5] = bfhi(ub.z);
            wB_[8 * k + 6] = bflo(ub.w); wB_[8 * k + 7] = bfhi(ub.w);
        }
    } else {
        const float* Wi = (const float*)Wih2r;
#pragma unroll
        for (int k = 0; k < 32; k++) {
            wA_[k] = Wi[rA * 32 + k];
            wB_[k] = Wi[rB * 32 + k];
        }
    }

    // ---- Phase B: LSTM1 recurrence on wave 0 (zero barriers) ----
    if (tid < 64) {
        int l = tid;
        float wA[32], wB[32];
        if (bf) {
            const uint32_t* w1 = (const uint32_t*)Whh1r;
#pragma unroll
            for (int k = 0; k < 16; k++) {
                uint32_t u = w1[l * 16 + k];
                wA[2 * k] = bflo(u); wA[2 * k + 1] = bfhi(u);
                uint32_t v = w1[(l + 64) * 16 + k];
                wB[2 * k] = bflo(v); wB[2 * k + 1] = bfhi(v);
            }
        } else {
            const float* w1 = (const float*)Whh1r;
#pragma unroll
            for (int k = 0; k < 32; k++) {
                wA[k] = w1[l * 32 + k];
                wB[k] = w1[(l + 64) * 32 + k];
            }
        }
        float za[12], zg[12];
#pragma unroll
        for (int t = 0; t < 12; t++) {
            za[t] = Z1[t * 4096 + b * 128 + l];
            zg[t] = Z1[t * 4096 + b * 128 + 64 + l];
        }
        if (l < 32) hb1[l] = 0.f;
        __threadfence_block();
        float c = 0.f;
        for (int t = 0; t < 12; t++) {
            float d0 = za[t], d1 = zg[t];
#pragma unroll
            for (int k = 0; k < 8; k++) {
                float4 h4 = *(const float4*)&hb1[4 * k];
                d0 += wA[4*k]*h4.x + wA[4*k+1]*h4.y + wA[4*k+2]*h4.z + wA[4*k+3]*h4.w;
                d1 += wB[4*k]*h4.x + wB[4*k+1]*h4.y + wB[4*k+2]*h4.z + wB[4*k+3]*h4.w;
            }
            float e0 = __shfl_xor(d0, 32, 64);
            float e1 = __shfl_xor(d1, 32, 64);
            if (l < 32) {
                c = sigmf(e0) * c + sigmf(d0) * tanhfast(d1);
                float h = sigmf(e1) * tanhfast(c);
                hb1[l] = h;
                h1s[t * 32 + l] = h;
            }
            __threadfence_block();
        }
    }
    if (tid < 128) hb[0][tid] = 0.f;
    __syncthreads();

    // ---- Phase C: Wih2 projection into registers (zin for gates 2qh, 2qh+1) ----
    float zA[12], zB[12];
#pragma unroll
    for (int t = 0; t < 12; t++) {
        const float4* hp = (const float4*)&h1s[t * 32];
        float a = zbA, c = zbB;
#pragma unroll
        for (int k = 0; k < 8; k++) {
            float4 h4 = hp[k];
            a += wA_[4*k]*h4.x + wA_[4*k+1]*h4.y + wA_[4*k+2]*h4.z + wA_[4*k+3]*h4.w;
            c += wB_[4*k]*h4.x + wB_[4*k+1]*h4.y + wB_[4*k+2]*h4.z + wB_[4*k+3]*h4.w;
        }
        zA[t] = a; zB[t] = c;
    }

    // ---- Phase D: LSTM2 recurrence, 1 barrier/step, K-split + shfl gate sum ----
    const float* W2f = (const float*)Whh2r;
    const float4* wq0 = (const float4*)(W2f + (0 * 128 + e) * 128 + qh * 64);
    const float4* wq1 = (const float4*)(W2f + (1 * 128 + e) * 128 + qh * 64);
    const float4* wq2 = (const float4*)(W2f + (2 * 128 + e) * 128 + qh * 64);
    const float4* wq3 = (const float4*)(W2f + (3 * 128 + e) * 128 + qh * 64);
    float c2 = 0.f;
#pragma unroll
    for (int t = 0; t < 12; t++) {
        const int cur = t & 1, nxt = cur ^ 1;
        const float4* hp = (const float4*)&hb[cur][qh * 64];
        float p0, p1, p2, p3;
        if (qh == 0) { p0 = zA[t]; p1 = zB[t]; p2 = 0.f;   p3 = 0.f;   }
        else         { p0 = 0.f;   p1 = 0.f;   p2 = zA[t]; p3 = zB[t]; }
        if (bf) {
#pragma unroll
            for (int k = 0; k < 8; k++) {
                float4 ha = hp[2 * k], hc = hp[2 * k + 1];
                uint4 u0 = wd[k], u1 = wd[8 + k], u2 = wd[16 + k], u3 = wd[24 + k];
                p0 += bflo(u0.x)*ha.x + bfhi(u0.x)*ha.y + bflo(u0.y)*ha.z + bfhi(u0.y)*ha.w
                    + bflo(u0.z)*hc.x + bfhi(u0.z)*hc.y + bflo(u0.w)*hc.z + bfhi(u0.w)*hc.w;
                p1 += bflo(u1.x)*ha.x + bfhi(u1.x)*ha.y + bflo(u1.y)*ha.z + bfhi(u1.y)*ha.w
                    + bflo(u1.z)*hc.x + bfhi(u1.z)*hc.y + bflo(u1.w)*hc.z + bfhi(u1.w)*hc.w;
                p2 += bflo(u2.x)*ha.x + bfhi(u2.x)*ha.y + bflo(u2.y)*ha.z + bfhi(u2.y)*ha.w
                    + bflo(u2.z)*hc.x + bfhi(u2.z)*hc.y + bflo(u2.w)*hc.z + bfhi(u2.w)*hc.w;
                p3 += bflo(u3.x)*ha.x + bfhi(u3.x)*ha.y + bflo(u3.y)*ha.z + bfhi(u3.y)*ha.w
                    + bflo(u3.z)*hc.x + bfhi(u3.z)*hc.y + bflo(u3.w)*hc.z + bfhi(u3.w)*hc.w;
            }
        } else {
#pragma unroll
            for (int k = 0; k < 16; k++) {
                float4 h4 = hp[k];
                float4 a0 = wq0[k], a1 = wq1[k], a2 = wq2[k], a3 = wq3[k];
                p0 += a0.x*h4.x + a0.y*h4.y + a0.z*h4.z + a0.w*h4.w;
                p1 += a1.x*h4.x + a1.y*h4.y + a1.z*h4.z + a1.w*h4.w;
                p2 += a2.x*h4.x + a2.y*h4.y + a2.z*h4.z + a2.w*h4.w;
                p3 += a3.x*h4.x + a3.y*h4.y + a3.z*h4.z + a3.w*h4.w;
            }
        }
        float z0 = p0 + __shfl_xor(p0, 32, 64);
        float z1 = p1 + __shfl_xor(p1, 32, 64);
        float z2 = p2 + __shfl_xor(p2, 32, 64);
        float z3 = p3 + __shfl_xor(p3, 32, 64);
        c2 = sigmf(z1) * c2 + sigmf(z0) * tanhfast(z2);
        float h = sigmf(z3) * tanhfast(c2);
        if (qh == 0) {
            hb[nxt][e] = h;
            if (t == 11) h2l[b * 128 + e] = h;
        }
        __syncthreads();
    }
}

// ---------- final linear (dual-path W) ----------
__global__ void __launch_bounds__(256) k_lin(const float* __restrict__ h2l,
                                             const void* __restrict__ Wraw,
                                             const float* __restrict__ bl,
                                             const int* __restrict__ flags,
                                             void* __restrict__ outv) {
    __shared__ float hl[8 * 128];
    int bg = blockIdx.y;
    for (int i = threadIdx.x; i < 1024; i += 256) hl[i] = h2l[bg * 1024 + i];
    __syncthreads();
    int o = blockIdx.x * 256 + threadIdx.x;
    float bb = bl[o];
    float acc[8];
#pragma unroll
    for (int b = 0; b < 8; b++) acc[b] = bb;
    int bf = flags[0];
    if (bf) {
        const uint4* wp = (const uint4*)((const uint16_t*)Wraw + o * 128);
        for (int k = 0; k < 16; k++) {
            uint4 u = wp[k];
            float w0 = bflo(u.x), w1 = bfhi(u.x), w2 = bflo(u.y), w3 = bfhi(u.y);
            float w4 = bflo(u.z), w5 = bfhi(u.z), w6 = bflo(u.w), w7 = bfhi(u.w);
#pragma unroll
            for (int b = 0; b < 8; b++) {
                const float* h8 = hl + b * 128 + k * 8;
                acc[b] += w0 * h8[0] + w1 * h8[1] + w2 * h8[2] + w3 * h8[3]
                        + w4 * h8[4] + w5 * h8[5] + w6 * h8[6] + w7 * h8[7];
            }
        }
    } else {
        const float4* wp = (const float4*)((const float*)Wraw + o * 128);
        for (int k = 0; k < 32; k++) {
            float4 w = wp[k];
#pragma unroll
            for (int b = 0; b < 8; b++) {
                const float* h4 = hl + b * 128 + k * 4;
                acc[b] += w.x * h4[0] + w.y * h4[1] + w.z * h4[2] + w.w * h4[3];
            }
        }
    }
    if (bf) {
        uint16_t* out = (uint16_t*)outv;
#pragma unroll
        for (int b = 0; b < 8; b++) out[(bg * 8 + b) * 18432 + o] = f2bf(acc[b]);
    } else {
        float* out = (float*)outv;
#pragma unroll
        for (int b = 0; b < 8; b++) out[(bg * 8 + b) * 18432 + o] = acc[b];
    }
}

extern "C" void kernel_launch(void* const* d_in, const int* in_sizes, int n_in,
                              void* d_out, int out_size, void* d_ws, size_t ws_size,
                              hipStream_t stream) {
    int E = in_sizes[1] / 2;

    float* ws = (float*)d_ws;
    int* flags = (int*)ws;          // [0]=bf16 [1]=stride [2]=gcount
    float* cWg   = ws + O_WG;
    float* cAtt  = ws + O_AS;
    float* cBias = ws + O_BIAS;
    float* cBih1 = ws + O_BIH1;
    float* cBhh1 = ws + O_BHH1;
    float* cBih2 = ws + O_BIH2;
    float* cBhh2 = ws + O_BHH2;
    float* cBlin = ws + O_BLIN;

    float* base = ws + O_END;
    float* a_s  = base;                            // 524288
    float* a_d  = a_s + 524288;                    // 524288
    int* deg    = (int*)(a_d + 524288);            // 65536
    int* offs   = deg + 65536;                     // 65536
    int* rank   = offs + 65536;                    // E
    int* ssrc   = rank + E;                        // E
    float* gT   = (float*)(ssrc + E);              // 786432
    float* Z1   = gT + 786432;                     // 49152
    float* h2l  = Z1 + 49152;                      // 4096
    size_t needed = (size_t)((h2l + 4096) - ws) * 4;
    if (ws_size < needed) return;

    k_pre<<<256, 256, 0, stream>>>(d_in[0], (const int*)d_in[1],
                                   d_in[2], d_in[3], d_in[4], d_in[5],
                                   d_in[8], d_in[9], d_in[12], d_in[13], d_in[15],
                                   ws, deg);
    k_nfa<<<2048, 256, 0, stream>>>(d_in[0], cWg, cAtt, flags,
                                    (const int*)d_in[1], E, deg, rank,
                                    a_s, a_d);
    k_scan<<<256, 256, 0, stream>>>(deg, offs, flags + 2);
    k_scatter<<<(E + 255) / 256, 256, 0, stream>>>((const int*)d_in[1], E, flags,
                                                   offs, rank, ssrc);
    k_agg<<<NTOT / 4, 256, 0, stream>>>(d_in[0], cWg, a_s, a_d, offs, deg, ssrc,
                                        cBias, flags, gT);
    k_z1<<<96, 256, 0, stream>>>(gT, d_in[6], cBih1, cBhh1, flags, Z1);
    k_tail<<<32, 256, 0, stream>>>(Z1, d_in[7], d_in[10], d_in[11],
                                   cBih2, cBhh2, flags, h2l);
    k_lin<<<dim3(72, 4), 256, 0, stream>>>(h2l, d_in[14], cBlin, flags, d_out);
}

// Round 2
// 388.604 us; speedup vs baseline: 1.1572x; 1.1572x over previous
//
#include <hip/hip_runtime.h>
#include <hip/hip_bf16.h>
#include <stdint.h>

#define NTOT 65536   // B * N_NODE
#define NNODE 2048
#define CIN 12

__device__ __forceinline__ float bf2f(uint32_t u) {
    union { uint32_t i; float f; } v; v.i = u << 16; return v.f;
}
__device__ __forceinline__ uint16_t f2bf(float f) {
    union { float f; uint32_t i; } v; v.f = f;
    uint32_t x = v.i;
    uint32_t r = x + 0x7fffu + ((x >> 16) & 1u);
    return (uint16_t)(r >> 16);
}
__device__ __forceinline__ float bflo(uint32_t u) { return bf2f(u & 0xffffu); }
__device__ __forceinline__ float bfhi(uint32_t u) { return bf2f(u >> 16); }
__device__ __forceinline__ float sigmf(float x) {
    return __builtin_amdgcn_rcpf(1.0f + __expf(-x));
}
__device__ __forceinline__ float tanhfast(float x) {
    float ex = __expf(2.0f * x);
    return 1.0f - 2.0f * __builtin_amdgcn_rcpf(ex + 1.0f);
}
__device__ __forceinline__ float lrelu(float v) { return v > 0.f ? v : 0.2f * v; }

// ws float offsets (flags[0]=bf16?, flags[1]=edge stride words, flags[2]=gcount)
#define O_WG   16
#define O_AS   1168
#define O_AD   1264
#define O_BIAS 1360
#define O_BIH1 1376
#define O_BHH1 1504
#define O_BIH2 1632
#define O_BHH2 2144
#define O_BLIN 2656
#define O_END  21088

__device__ __forceinline__ void cvt(const void* s, float* d, int i, int bf) {
    d[i] = bf ? bf2f(((const uint16_t*)s)[i]) : ((const float*)s)[i];
}

// ---------- fused: dtype detect + small-tensor conv + zero ----------
__global__ void __launch_bounds__(256) k_pre(
    const void* x, const int* __restrict__ e32,
    const void* wg, const void* as_, const void* ad_, const void* bs,
    const void* b1, const void* bb1, const void* b2, const void* bb2,
    const void* bl, float* __restrict__ ws, int* __restrict__ deg) {
    int tid = threadIdx.x, lane = tid & 63;
    uint32_t u = ((const uint16_t*)x)[2 * lane];
    uint32_t ex = (u >> 7) & 0xFF;
    bool sane = (ex >= 0x60 && ex <= 0x9F) || (u == 0);
    unsigned long long bsx = __ballot(sane);
    bool hi_zero = (e32[2 * lane + 1] == 0);
    unsigned long long bz = __ballot(hi_zero);
    int bf = (__popcll(bsx) >= 52) ? 1 : 0;
    int st = (__popcll(bz) == 64) ? 2 : 1;
    if (blockIdx.x == 0 && tid == 0) {
        ((int*)ws)[0] = bf; ((int*)ws)[1] = st; ((int*)ws)[2] = 0;
    }
    deg[blockIdx.x * 256 + tid] = 0;
    int i = blockIdx.x * 256 + tid;
    if (i < 1152)  { cvt(wg,  ws + O_WG,   i, bf); return; } i -= 1152;
    if (i < 96)    { cvt(as_, ws + O_AS,   i, bf); return; } i -= 96;
    if (i < 96)    { cvt(ad_, ws + O_AD,   i, bf); return; } i -= 96;
    if (i < 12)    { cvt(bs,  ws + O_BIAS, i, bf); return; } i -= 12;
    if (i < 128)   { cvt(b1,  ws + O_BIH1, i, bf); return; } i -= 128;
    if (i < 128)   { cvt(bb1, ws + O_BHH1, i, bf); return; } i -= 128;
    if (i < 512)   { cvt(b2,  ws + O_BIH2, i, bf); return; } i -= 512;
    if (i < 512)   { cvt(bb2, ws + O_BHH2, i, bf); return; } i -= 512;
    if (i < 18432) { cvt(bl,  ws + O_BLIN, i, bf); }
}

// ---------- fused attention scores + edge histogram ----------
__global__ void __launch_bounds__(256) k_nfa(const void* __restrict__ xraw,
                                             const float* __restrict__ Wg,
                                             const float* __restrict__ att,
                                             const int* __restrict__ flags,
                                             const int* __restrict__ e, int E,
                                             int* __restrict__ deg, int* __restrict__ rank,
                                             float* __restrict__ a_s, float* __restrict__ a_d) {
    __shared__ float sx[384];
    __shared__ float sw[1152];
    __shared__ float satt[192];
    __shared__ float sh[3072];
    int tid = threadIdx.x;
    int n0 = blockIdx.x * 32;
    if (flags[0]) {
        const uint32_t* xp = (const uint32_t*)xraw;
        for (int i = tid; i < 192; i += 256) {
            uint32_t u = xp[n0 * 6 + i];
            sx[2 * i] = bflo(u); sx[2 * i + 1] = bfhi(u);
        }
    } else {
        const float* xp = (const float*)xraw;
        for (int i = tid; i < 384; i += 256) sx[i] = xp[n0 * 12 + i];
    }
    for (int i = tid; i < 1152; i += 256) sw[i] = Wg[i];
    if (tid < 192) satt[tid] = att[tid];
    {
        long st = flags[1];
        int chunk = (E + gridDim.x - 1) / gridDim.x;
        int ebase = blockIdx.x * chunk;
        int eend = min(ebase + chunk, E);
        for (int i = ebase + tid; i < eend; i += 256) {
            int d = e[st * (E + i)];
            rank[i] = atomicAdd(&deg[d], 1);
        }
    }
    __syncthreads();
#pragma unroll
    for (int r = 0; r < 12; r++) {
        int idx = r * 256 + tid;
        int n = idx / 96, o = idx % 96;
        float acc = 0.f;
#pragma unroll
        for (int k = 0; k < 12; k++) acc += sx[n * 12 + k] * sw[k * 96 + o];
        sh[idx] = acc;
    }
    __syncthreads();
    {
        int nl = tid >> 3, h = tid & 7;
        const float* hr = sh + nl * 96 + h * 12;
        float s = 0.f, dd = 0.f;
#pragma unroll
        for (int c = 0; c < 12; c++) {
            float v = hr[c];
            s += v * satt[h * 12 + c];
            dd += v * satt[96 + h * 12 + c];
        }
        a_s[n0 * 8 + tid] = s;
        a_d[n0 * 8 + tid] = dd;
    }
}

// ---------- scan: local exclusive scan + atomic global base ----------
__global__ void k_scan(const int* __restrict__ deg, int* __restrict__ offs,
                       int* __restrict__ gcount) {
    __shared__ int s[256];
    __shared__ int base;
    int t = threadIdx.x, i = blockIdx.x * 256 + t;
    int v = deg[i];
    s[t] = v; __syncthreads();
    for (int off = 1; off < 256; off <<= 1) {
        int a = (t >= off) ? s[t - off] : 0;
        __syncthreads();
        s[t] += a;
        __syncthreads();
    }
    if (t == 255) base = atomicAdd(gcount, s[255]);
    __syncthreads();
    offs[i] = base + s[t] - v;
}

__global__ void k_scatter(const int* __restrict__ e, int E, const int* __restrict__ flags,
                          const int* __restrict__ offs, const int* __restrict__ rank,
                          int* __restrict__ ssrc) {
    int i = blockIdx.x * 256 + threadIdx.x;
    if (i < E) {
        long st = flags[1];
        int s = e[st * i];
        int d = e[st * (E + i)];
        ssrc[offs[d] + rank[i]] = s;
    }
}

// ---------- GAT aggregation: aggregate x (12ch), project through Wg per node ----------
__global__ void __launch_bounds__(256) k_agg(
    const void* __restrict__ xraw, const float* __restrict__ WgG,
    const float* __restrict__ a_s, const float* __restrict__ a_d,
    const int* __restrict__ offs, const int* __restrict__ deg,
    const int* __restrict__ ssrc, const float* __restrict__ bias,
    const int* __restrict__ flags, float* __restrict__ gT) {
    __shared__ float swg[1152];
    __shared__ float sres[4][12];
    int tid = threadIdx.x, wave = tid >> 6, lane = tid & 63;
    for (int i = tid; i < 1152; i += 256) swg[i] = WgG[i];
    __syncthreads();
    int node = blockIdx.x * 4 + wave;
    int beg = offs[node], d = deg[node];
    int sub = lane >> 3, h = lane & 7;
    float adh = a_d[node * 8 + h];
    int bf = flags[0];
    float acc[12];
    float wsum = 0.f;
#pragma unroll
    for (int c = 0; c < 12; c++) acc[c] = 0.f;
    if (sub == 0) {
        float w = __expf(lrelu(a_s[node * 8 + h] + adh));
        wsum = w;
        if (bf) {
            const uint2* xp = (const uint2*)((const uint16_t*)xraw + node * 12);
            uint2 u0 = xp[0], u1 = xp[1], u2 = xp[2];
            acc[0] = w * bflo(u0.x); acc[1] = w * bfhi(u0.x);
            acc[2] = w * bflo(u0.y); acc[3] = w * bfhi(u0.y);
            acc[4] = w * bflo(u1.x); acc[5] = w * bfhi(u1.x);
            acc[6] = w * bflo(u1.y); acc[7] = w * bfhi(u1.y);
            acc[8] = w * bflo(u2.x); acc[9] = w * bfhi(u2.x);
            acc[10] = w * bflo(u2.y); acc[11] = w * bfhi(u2.y);
        } else {
            const float4* xp = (const float4*)((const float*)xraw + node * 12);
            float4 v0 = xp[0], v1 = xp[1], v2 = xp[2];
            acc[0] = w * v0.x; acc[1] = w * v0.y; acc[2] = w * v0.z; acc[3] = w * v0.w;
            acc[4] = w * v1.x; acc[5] = w * v1.y; acc[6] = w * v1.z; acc[7] = w * v1.w;
            acc[8] = w * v2.x; acc[9] = w * v2.y; acc[10] = w * v2.z; acc[11] = w * v2.w;
        }
    }
    for (int base = 0; base < d; base += 8) {
        int k = base + sub;
        if (k < d) {
            int s = ssrc[beg + k];
            float w = __expf(lrelu(a_s[s * 8 + h] + adh));
            wsum += w;
            if (bf) {
                const uint2* xp = (const uint2*)((const uint16_t*)xraw + s * 12);
                uint2 u0 = xp[0], u1 = xp[1], u2 = xp[2];
                acc[0] += w * bflo(u0.x); acc[1] += w * bfhi(u0.x);
                acc[2] += w * bflo(u0.y); acc[3] += w * bfhi(u0.y);
                acc[4] += w * bflo(u1.x); acc[5] += w * bfhi(u1.x);
                acc[6] += w * bflo(u1.y); acc[7] += w * bfhi(u1.y);
                acc[8] += w * bflo(u2.x); acc[9] += w * bfhi(u2.x);
                acc[10] += w * bflo(u2.y); acc[11] += w * bfhi(u2.y);
            } else {
                const float4* xp = (const float4*)((const float*)xraw + s * 12);
                float4 v0 = xp[0], v1 = xp[1], v2 = xp[2];
                acc[0] += w * v0.x; acc[1] += w * v0.y; acc[2] += w * v0.z; acc[3] += w * v0.w;
                acc[4] += w * v1.x; acc[5] += w * v1.y; acc[6] += w * v1.z; acc[7] += w * v1.w;
                acc[8] += w * v2.x; acc[9] += w * v2.y; acc[10] += w * v2.z; acc[11] += w * v2.w;
            }
        }
    }
#pragma unroll
    for (int off = 8; off <= 32; off <<= 1) {
        wsum += __shfl_xor(wsum, off, 64);
#pragma unroll
        for (int c = 0; c < 12; c++) acc[c] += __shfl_xor(acc[c], off, 64);
    }
    float invw = 1.f / wsum;
#pragma unroll
    for (int c = 0; c < 12; c++) acc[c] *= invw;
    float p0 = 0.f, p1 = 0.f;
    const float* wcol = swg + h * 12;
#pragma unroll
    for (int k = 0; k < 12; k++) {
        float a = acc[k];
        p0 += a * wcol[k * 96 + sub];
        p1 += a * wcol[k * 96 + sub + 4];
    }
#pragma unroll
    for (int off = 1; off <= 4; off <<= 1) {
        p0 += __shfl_xor(p0, off, 64);
        p1 += __shfl_xor(p1, off, 64);
    }
    if (h == 0) {
        sres[wave][sub] = p0;
        if (sub >= 4) sres[wave][sub + 4] = p1;
    }
    __syncthreads();
    if (tid < 48) {
        int no = tid / 12, c = tid % 12;
        gT[c * NTOT + blockIdx.x * 4 + no] = sres[no][c] * 0.125f + bias[c];
    }
}

// ---------- Z1: 4 batches per block, weight loads shared ----------
__global__ void __launch_bounds__(256) k_z1(const float* __restrict__ gT,
                                            const void* __restrict__ Wraw,
                                            const float* __restrict__ b1,
                                            const float* __restrict__ b2,
                                            const int* __restrict__ flags,
                                            float* __restrict__ Z1) {
    int t = blockIdx.x >> 3, bg = (blockIdx.x & 7) * 4;
    __shared__ float sv[4][2048];
    __shared__ float zp[2][4][128];
    int tid = threadIdx.x;
#pragma unroll
    for (int q = 0; q < 4; q++)
        for (int v = tid; v < 2048; v += 256) sv[q][v] = gT[t * NTOT + (bg + q) * NNODE + v];
    __syncthreads();
    int row = tid & 127, half = tid >> 7;
    float a0 = 0.f, a1 = 0.f, a2 = 0.f, a3 = 0.f;
    int hbase = half * 1024;
    if (flags[0]) {
        const uint4* wp = (const uint4*)((const uint16_t*)Wraw + row * 2048 + hbase);
        for (int k = 0; k < 128; k++) {
            uint4 u = wp[k];
            float w0 = bflo(u.x), w1 = bfhi(u.x), w2 = bflo(u.y), w3 = bfhi(u.y);
            float w4 = bflo(u.z), w5 = bfhi(u.z), w6 = bflo(u.w), w7 = bfhi(u.w);
#pragma unroll
            for (int q = 0; q < 4; q++) {
                float4 A = *(const float4*)&sv[q][hbase + 8 * k];
                float4 B = *(const float4*)&sv[q][hbase + 8 * k + 4];
                float r = w0 * A.x + w1 * A.y + w2 * A.z + w3 * A.w
                        + w4 * B.x + w5 * B.y + w6 * B.z + w7 * B.w;
                if (q == 0) a0 += r; else if (q == 1) a1 += r;
                else if (q == 2) a2 += r; else a3 += r;
            }
        }
    } else {
        const float4* wp = (const float4*)((const float*)Wraw + row * 2048 + hbase);
        for (int k = 0; k < 256; k++) {
            float4 w = wp[k];
#pragma unroll
            for (int q = 0; q < 4; q++) {
                float4 A = *(const float4*)&sv[q][hbase + 4 * k];
                float r = w.x * A.x + w.y * A.y + w.z * A.z + w.w * A.w;
                if (q == 0) a0 += r; else if (q == 1) a1 += r;
                else if (q == 2) a2 += r; else a3 += r;
            }
        }
    }
    zp[half][0][row] = a0; zp[half][1][row] = a1;
    zp[half][2][row] = a2; zp[half][3][row] = a3;
    __syncthreads();
    if (tid < 128) {
        float bb = b1[tid] + b2[tid];
#pragma unroll
        for (int q = 0; q < 4; q++)
            Z1[t * 4096 + (bg + q) * 128 + tid] = zp[0][q][tid] + zp[1][q][tid] + bb;
    }
}

// ---------- fused tail: LSTM1 + Wih2 proj + LSTM2 ----------
// 512 threads = 8 waves. LSTM2 thread layout: lane = h*32 + gp*16 + (e&15),
// e = wave*16 + (lane&15). gp=0 owns rows {i(e), f(e)}, gp=1 owns {g(e), o(e)};
// h = K-half (64 cols). Each thread: 2 row-partials over its half with 16 uint4
// (64 VGPR) pinned weights. Cross-half sum via shfl_xor(32), gate exchange via
// shfl_xor(16). One barrier/step (double-buffered hb). z-inputs in registers
// (zinA/zinB[12]), zs2 LDS eliminated.
__global__ void __launch_bounds__(512) k_tail(
    const float* __restrict__ Z1,
    const void* __restrict__ Whh1r,
    const void* __restrict__ Wih2r, const void* __restrict__ Whh2r,
    const float* __restrict__ b2i, const float* __restrict__ b2h,
    const int* __restrict__ flags, float* __restrict__ h2l) {
    int b = blockIdx.x, tid = threadIdx.x;
    __shared__ __align__(16) float h1s[12 * 32];
    __shared__ __align__(16) float hb1[32];
    __shared__ __align__(16) float hb[2][128];
    int bf = flags[0];
    int lane = tid & 63, wv = tid >> 6;
    int kh = lane >> 5;            // K-half
    int gp = (lane >> 4) & 1;      // gate pair: 0 -> (i,f), 1 -> (g,o)
    int e = wv * 16 + (lane & 15); // element 0..127
    int rA = gp * 256 + e;         // row of gate i (or g)
    int rB = gp * 256 + 128 + e;   // row of gate f (or o)

    // ---- Phase B: LSTM1 recurrence on wave 0 (zero barriers) ----
    if (tid < 64) {
        int l = tid;
        float wA[32], wB[32];
        if (bf) {
            const uint32_t* w1 = (const uint32_t*)Whh1r;
#pragma unroll
            for (int k = 0; k < 16; k++) {
                uint32_t u = w1[l * 16 + k];
                wA[2 * k] = bflo(u); wA[2 * k + 1] = bfhi(u);
                uint32_t v = w1[(l + 64) * 16 + k];
                wB[2 * k] = bflo(v); wB[2 * k + 1] = bfhi(v);
            }
        } else {
            const float* w1 = (const float*)Whh1r;
#pragma unroll
            for (int k = 0; k < 32; k++) {
                wA[k] = w1[l * 32 + k];
                wB[k] = w1[(l + 64) * 32 + k];
            }
        }
        float za[12], zg[12];
#pragma unroll
        for (int t = 0; t < 12; t++) {
            za[t] = Z1[t * 4096 + b * 128 + l];
            zg[t] = Z1[t * 4096 + b * 128 + 64 + l];
        }
        if (l < 32) hb1[l] = 0.f;
        __threadfence_block();
        float c = 0.f;
        for (int t = 0; t < 12; t++) {
            float d0 = za[t], d1 = zg[t];
#pragma unroll
            for (int k = 0; k < 8; k++) {
                float4 h4 = *(const float4*)&hb1[4 * k];
                d0 += wA[4*k]*h4.x + wA[4*k+1]*h4.y + wA[4*k+2]*h4.z + wA[4*k+3]*h4.w;
                d1 += wB[4*k]*h4.x + wB[4*k+1]*h4.y + wB[4*k+2]*h4.z + wB[4*k+3]*h4.w;
            }
            float e0 = __shfl_xor(d0, 32, 64);
            float e1 = __shfl_xor(d1, 32, 64);
            if (l < 32) {
                c = sigmf(e0) * c + sigmf(d0) * tanhfast(d1);
                float h = sigmf(e1) * tanhfast(c);
                hb1[l] = h;
                h1s[t * 32 + l] = h;
            }
            __threadfence_block();
        }
    }

    // ---- pin weights (issued here so Phase-B regs on wave0 are dead first;
    //      waves 1..7 reach this immediately and overlap loads with Phase B) ----
    float zbA = b2i[rA] + b2h[rA];
    float zbB = b2i[rB] + b2h[rB];
    uint4 wdA[8], wdB[8];   // Whh2 rows rA,rB, K-half kh (64 bf16 each)
    uint4 wiA[4], wiB[4];   // Wih2 rows rA,rB (32 bf16 each)
    if (bf) {
        const uint16_t* W2 = (const uint16_t*)Whh2r;
        const uint4* pA = (const uint4*)(W2 + rA * 128 + kh * 64);
        const uint4* pB = (const uint4*)(W2 + rB * 128 + kh * 64);
#pragma unroll
        for (int k = 0; k < 8; k++) { wdA[k] = pA[k]; wdB[k] = pB[k]; }
        const uint4* qA = (const uint4*)((const uint16_t*)Wih2r + rA * 32);
        const uint4* qB = (const uint4*)((const uint16_t*)Wih2r + rB * 32);
#pragma unroll
        for (int k = 0; k < 4; k++) { wiA[k] = qA[k]; wiB[k] = qB[k]; }
    }
    if (tid < 128) hb[0][tid] = 0.f;
    __syncthreads();

    // ---- Phase C: Wih2 projection into registers (rows rA,rB, all 12 t) ----
    float zinA[12], zinB[12];
    if (bf) {
#pragma unroll
        for (int t = 0; t < 12; t++) {
            const float4* hp = (const float4*)&h1s[t * 32];
            float a = zbA, c = zbB;
#pragma unroll
            for (int k = 0; k < 4; k++) {
                float4 h0 = hp[2 * k], h1 = hp[2 * k + 1];
                uint4 ua = wiA[k], ub = wiB[k];
                a += bflo(ua.x)*h0.x + bfhi(ua.x)*h0.y + bflo(ua.y)*h0.z + bfhi(ua.y)*h0.w
                   + bflo(ua.z)*h1.x + bfhi(ua.z)*h1.y + bflo(ua.w)*h1.z + bfhi(ua.w)*h1.w;
                c += bflo(ub.x)*h0.x + bfhi(ub.x)*h0.y + bflo(ub.y)*h0.z + bfhi(ub.y)*h0.w
                   + bflo(ub.z)*h1.x + bfhi(ub.z)*h1.y + bflo(ub.w)*h1.z + bfhi(ub.w)*h1.w;
            }
            zinA[t] = a; zinB[t] = c;
        }
    } else {
        const float* Wi = (const float*)Wih2r;
        const float4* qA = (const float4*)(Wi + rA * 32);
        const float4* qB = (const float4*)(Wi + rB * 32);
#pragma unroll
        for (int t = 0; t < 12; t++) {
            const float4* hp = (const float4*)&h1s[t * 32];
            float a = zbA, c = zbB;
#pragma unroll
            for (int k = 0; k < 8; k++) {
                float4 h4 = hp[k];
                float4 qa = qA[k], qb = qB[k];
                a += qa.x*h4.x + qa.y*h4.y + qa.z*h4.z + qa.w*h4.w;
                c += qb.x*h4.x + qb.y*h4.y + qb.z*h4.z + qb.w*h4.w;
            }
            zinA[t] = a; zinB[t] = c;
        }
    }

    // ---- Phase D: LSTM2 recurrence, 1 barrier/step, shfl gate exchange ----
    const float* W2f = (const float*)Whh2r;
    const float4* wfA = (const float4*)(W2f + rA * 128 + kh * 64);
    const float4* wfB = (const float4*)(W2f + rB * 128 + kh * 64);
    float c2 = 0.f;
#pragma unroll
    for (int t = 0; t < 12; t++) {
        const int cur = t & 1, nxt = cur ^ 1;
        const float4* hp = (const float4*)&hb[cur][kh * 64];
        float pA = (kh == 0) ? zinA[t] : 0.f;
        float pB = (kh == 0) ? zinB[t] : 0.f;
        if (bf) {
#pragma unroll
            for (int k = 0; k < 8; k++) {
                float4 ha = hp[2 * k], hc = hp[2 * k + 1];
                uint4 ua = wdA[k], ub = wdB[k];
                pA += bflo(ua.x)*ha.x + bfhi(ua.x)*ha.y + bflo(ua.y)*ha.z + bfhi(ua.y)*ha.w
                    + bflo(ua.z)*hc.x + bfhi(ua.z)*hc.y + bflo(ua.w)*hc.z + bfhi(ua.w)*hc.w;
                pB += bflo(ub.x)*ha.x + bfhi(ub.x)*ha.y + bflo(ub.y)*ha.z + bfhi(ub.y)*ha.w
                    + bflo(ub.z)*hc.x + bfhi(ub.z)*hc.y + bflo(ub.w)*hc.z + bfhi(ub.w)*hc.w;
            }
        } else {
#pragma unroll
            for (int k = 0; k < 16; k++) {
                float4 h4 = hp[k];
                float4 qa = wfA[k], qb = wfB[k];
                pA += qa.x*h4.x + qa.y*h4.y + qa.z*h4.z + qa.w*h4.w;
                pB += qb.x*h4.x + qb.y*h4.y + qb.z*h4.z + qb.w*h4.w;
            }
        }
        // cross-half sum (lane ^ 32): both halves now hold full z for rows rA,rB
        float zA = pA + __shfl_xor(pA, 32, 64);
        float zB = pB + __shfl_xor(pB, 32, 64);
        // gate exchange (lane ^ 16): gp0 lanes receive (g,o) from gp1 partner
        float zg_ = __shfl_xor(zA, 16, 64);
        float zo_ = __shfl_xor(zB, 16, 64);
        if (gp == 0) {
            c2 = sigmf(zB) * c2 + sigmf(zA) * tanhfast(zg_);
            float hh = sigmf(zo_) * tanhfast(c2);
            if (kh == 0) {
                hb[nxt][e] = hh;
                if (t == 11) h2l[b * 128 + e] = hh;
            }
        }
        __syncthreads();
    }
}

// ---------- final linear (dual-path W) ----------
__global__ void __launch_bounds__(256) k_lin(const float* __restrict__ h2l,
                                             const void* __restrict__ Wraw,
                                             const float* __restrict__ bl,
                                             const int* __restrict__ flags,
                                             void* __restrict__ outv) {
    __shared__ float hl[8 * 128];
    int bg = blockIdx.y;
    for (int i = threadIdx.x; i < 1024; i += 256) hl[i] = h2l[bg * 1024 + i];
    __syncthreads();
    int o = blockIdx.x * 256 + threadIdx.x;
    float bb = bl[o];
    float acc[8];
#pragma unroll
    for (int b = 0; b < 8; b++) acc[b] = bb;
    int bf = flags[0];
    if (bf) {
        const uint4* wp = (const uint4*)((const uint16_t*)Wraw + o * 128);
        for (int k = 0; k < 16; k++) {
            uint4 u = wp[k];
            float w0 = bflo(u.x), w1 = bfhi(u.x), w2 = bflo(u.y), w3 = bfhi(u.y);
            float w4 = bflo(u.z), w5 = bfhi(u.z), w6 = bflo(u.w), w7 = bfhi(u.w);
#pragma unroll
            for (int b = 0; b < 8; b++) {
                const float* h8 = hl + b * 128 + k * 8;
                acc[b] += w0 * h8[0] + w1 * h8[1] + w2 * h8[2] + w3 * h8[3]
                        + w4 * h8[4] + w5 * h8[5] + w6 * h8[6] + w7 * h8[7];
            }
        }
    } else {
        const float4* wp = (const float4*)((const float*)Wraw + o * 128);
        for (int k = 0; k < 32; k++) {
            float4 w = wp[k];
#pragma unroll
            for (int b = 0; b < 8; b++) {
                const float* h4 = hl + b * 128 + k * 4;
                acc[b] += w.x * h4[0] + w.y * h4[1] + w.z * h4[2] + w.w * h4[3];
            }
        }
    }
    if (bf) {
        uint16_t* out = (uint16_t*)outv;
#pragma unroll
        for (int b = 0; b < 8; b++) out[(bg * 8 + b) * 18432 + o] = f2bf(acc[b]);
    } else {
        float* out = (float*)outv;
#pragma unroll
        for (int b = 0; b < 8; b++) out[(bg * 8 + b) * 18432 + o] = acc[b];
    }
}

extern "C" void kernel_launch(void* const* d_in, const int* in_sizes, int n_in,
                              void* d_out, int out_size, void* d_ws, size_t ws_size,
                              hipStream_t stream) {
    int E = in_sizes[1] / 2;

    float* ws = (float*)d_ws;
    int* flags = (int*)ws;          // [0]=bf16 [1]=stride [2]=gcount
    float* cWg   = ws + O_WG;
    float* cAtt  = ws + O_AS;
    float* cBias = ws + O_BIAS;
    float* cBih1 = ws + O_BIH1;
    float* cBhh1 = ws + O_BHH1;
    float* cBih2 = ws + O_BIH2;
    float* cBhh2 = ws + O_BHH2;
    float* cBlin = ws + O_BLIN;

    float* base = ws + O_END;
    float* a_s  = base;                            // 524288
    float* a_d  = a_s + 524288;                    // 524288
    int* deg    = (int*)(a_d + 524288);            // 65536
    int* offs   = deg + 65536;                     // 65536
    int* rank   = offs + 65536;                    // E
    int* ssrc   = rank + E;                        // E
    float* gT   = (float*)(ssrc + E);              // 786432
    float* Z1   = gT + 786432;                     // 49152
    float* h2l  = Z1 + 49152;                      // 4096
    size_t needed = (size_t)((h2l + 4096) - ws) * 4;
    if (ws_size < needed) return;

    k_pre<<<256, 256, 0, stream>>>(d_in[0], (const int*)d_in[1],
                                   d_in[2], d_in[3], d_in[4], d_in[5],
                                   d_in[8], d_in[9], d_in[12], d_in[13], d_in[15],
                                   ws, deg);
    k_nfa<<<2048, 256, 0, stream>>>(d_in[0], cWg, cAtt, flags,
                                    (const int*)d_in[1], E, deg, rank,
                                    a_s, a_d);
    k_scan<<<256, 256, 0, stream>>>(deg, offs, flags + 2);
    k_scatter<<<(E + 255) / 256, 256, 0, stream>>>((const int*)d_in[1], E, flags,
                                                   offs, rank, ssrc);
    k_agg<<<NTOT / 4, 256, 0, stream>>>(d_in[0], cWg, a_s, a_d, offs, deg, ssrc,
                                        cBias, flags, gT);
    k_z1<<<96, 256, 0, stream>>>(gT, d_in[6], cBih1, cBhh1, flags, Z1);
    k_tail<<<32, 512, 0, stream>>>(Z1, d_in[7], d_in[10], d_in[11],
                                   cBih2, cBhh2, flags, h2l);
    k_lin<<<dim3(72, 4), 256, 0, stream>>>(h2l, d_in[14], cBlin, flags, d_out);
}

// Round 3
// 382.079 us; speedup vs baseline: 1.1770x; 1.0171x over previous
//
#include <hip/hip_runtime.h>
#include <hip/hip_bf16.h>
#include <stdint.h>

#define NTOT 65536   // B * N_NODE
#define NNODE 2048
#define CIN 12

__device__ __forceinline__ float bf2f(uint32_t u) {
    union { uint32_t i; float f; } v; v.i = u << 16; return v.f;
}
__device__ __forceinline__ uint16_t f2bf(float f) {
    union { float f; uint32_t i; } v; v.f = f;
    uint32_t x = v.i;
    uint32_t r = x + 0x7fffu + ((x >> 16) & 1u);
    return (uint16_t)(r >> 16);
}
__device__ __forceinline__ float bflo(uint32_t u) { return bf2f(u & 0xffffu); }
__device__ __forceinline__ float bfhi(uint32_t u) { return bf2f(u >> 16); }
__device__ __forceinline__ float sigmf(float x) {
    return __builtin_amdgcn_rcpf(1.0f + __expf(-x));
}
__device__ __forceinline__ float tanhfast(float x) {
    float ex = __expf(2.0f * x);
    return 1.0f - 2.0f * __builtin_amdgcn_rcpf(ex + 1.0f);
}
__device__ __forceinline__ float lrelu(float v) { return v > 0.f ? v : 0.2f * v; }

// ws float offsets (flags[0]=bf16?, flags[1]=edge stride words, flags[2]=gcount)
#define O_WG   16
#define O_AS   1168
#define O_AD   1264
#define O_BIAS 1360
#define O_BIH1 1376
#define O_BHH1 1504
#define O_BIH2 1632
#define O_BHH2 2144
#define O_BLIN 2656
#define O_END  21088

__device__ __forceinline__ void cvt(const void* s, float* d, int i, int bf) {
    d[i] = bf ? bf2f(((const uint16_t*)s)[i]) : ((const float*)s)[i];
}

// ---------- fused: dtype detect + small-tensor conv + zero ----------
__global__ void __launch_bounds__(256) k_pre(
    const void* x, const int* __restrict__ e32,
    const void* wg, const void* as_, const void* ad_, const void* bs,
    const void* b1, const void* bb1, const void* b2, const void* bb2,
    const void* bl, float* __restrict__ ws, int* __restrict__ deg) {
    int tid = threadIdx.x, lane = tid & 63;
    uint32_t u = ((const uint16_t*)x)[2 * lane];
    uint32_t ex = (u >> 7) & 0xFF;
    bool sane = (ex >= 0x60 && ex <= 0x9F) || (u == 0);
    unsigned long long bsx = __ballot(sane);
    bool hi_zero = (e32[2 * lane + 1] == 0);
    unsigned long long bz = __ballot(hi_zero);
    int bf = (__popcll(bsx) >= 52) ? 1 : 0;
    int st = (__popcll(bz) == 64) ? 2 : 1;
    if (blockIdx.x == 0 && tid == 0) {
        ((int*)ws)[0] = bf; ((int*)ws)[1] = st; ((int*)ws)[2] = 0;
    }
    deg[blockIdx.x * 256 + tid] = 0;
    int i = blockIdx.x * 256 + tid;
    if (i < 1152)  { cvt(wg,  ws + O_WG,   i, bf); return; } i -= 1152;
    if (i < 96)    { cvt(as_, ws + O_AS,   i, bf); return; } i -= 96;
    if (i < 96)    { cvt(ad_, ws + O_AD,   i, bf); return; } i -= 96;
    if (i < 12)    { cvt(bs,  ws + O_BIAS, i, bf); return; } i -= 12;
    if (i < 128)   { cvt(b1,  ws + O_BIH1, i, bf); return; } i -= 128;
    if (i < 128)   { cvt(bb1, ws + O_BHH1, i, bf); return; } i -= 128;
    if (i < 512)   { cvt(b2,  ws + O_BIH2, i, bf); return; } i -= 512;
    if (i < 512)   { cvt(bb2, ws + O_BHH2, i, bf); return; } i -= 512;
    if (i < 18432) { cvt(bl,  ws + O_BLIN, i, bf); }
}

// ---------- fused attention scores + edge histogram ----------
__global__ void __launch_bounds__(256) k_nfa(const void* __restrict__ xraw,
                                             const float* __restrict__ Wg,
                                             const float* __restrict__ att,
                                             const int* __restrict__ flags,
                                             const int* __restrict__ e, int E,
                                             int* __restrict__ deg, int* __restrict__ rank,
                                             float* __restrict__ a_s, float* __restrict__ a_d) {
    __shared__ float sx[384];
    __shared__ float sw[1152];
    __shared__ float satt[192];
    __shared__ float sh[3072];
    int tid = threadIdx.x;
    int n0 = blockIdx.x * 32;
    if (flags[0]) {
        const uint32_t* xp = (const uint32_t*)xraw;
        for (int i = tid; i < 192; i += 256) {
            uint32_t u = xp[n0 * 6 + i];
            sx[2 * i] = bflo(u); sx[2 * i + 1] = bfhi(u);
        }
    } else {
        const float* xp = (const float*)xraw;
        for (int i = tid; i < 384; i += 256) sx[i] = xp[n0 * 12 + i];
    }
    for (int i = tid; i < 1152; i += 256) sw[i] = Wg[i];
    if (tid < 192) satt[tid] = att[tid];
    {
        long st = flags[1];
        int chunk = (E + gridDim.x - 1) / gridDim.x;
        int ebase = blockIdx.x * chunk;
        int eend = min(ebase + chunk, E);
        for (int i = ebase + tid; i < eend; i += 256) {
            int d = e[st * (E + i)];
            rank[i] = atomicAdd(&deg[d], 1);
        }
    }
    __syncthreads();
#pragma unroll
    for (int r = 0; r < 12; r++) {
        int idx = r * 256 + tid;
        int n = idx / 96, o = idx % 96;
        float acc = 0.f;
#pragma unroll
        for (int k = 0; k < 12; k++) acc += sx[n * 12 + k] * sw[k * 96 + o];
        sh[idx] = acc;
    }
    __syncthreads();
    {
        int nl = tid >> 3, h = tid & 7;
        const float* hr = sh + nl * 96 + h * 12;
        float s = 0.f, dd = 0.f;
#pragma unroll
        for (int c = 0; c < 12; c++) {
            float v = hr[c];
            s += v * satt[h * 12 + c];
            dd += v * satt[96 + h * 12 + c];
        }
        a_s[n0 * 8 + tid] = s;
        a_d[n0 * 8 + tid] = dd;
    }
}

// ---------- scan: local exclusive scan + atomic global base ----------
__global__ void k_scan(const int* __restrict__ deg, int* __restrict__ offs,
                       int* __restrict__ gcount) {
    __shared__ int s[256];
    __shared__ int base;
    int t = threadIdx.x, i = blockIdx.x * 256 + t;
    int v = deg[i];
    s[t] = v; __syncthreads();
    for (int off = 1; off < 256; off <<= 1) {
        int a = (t >= off) ? s[t - off] : 0;
        __syncthreads();
        s[t] += a;
        __syncthreads();
    }
    if (t == 255) base = atomicAdd(gcount, s[255]);
    __syncthreads();
    offs[i] = base + s[t] - v;
}

__global__ void k_scatter(const int* __restrict__ e, int E, const int* __restrict__ flags,
                          const int* __restrict__ offs, const int* __restrict__ rank,
                          int* __restrict__ ssrc) {
    int i = blockIdx.x * 256 + threadIdx.x;
    if (i < E) {
        long st = flags[1];
        int s = e[st * i];
        int d = e[st * (E + i)];
        ssrc[offs[d] + rank[i]] = s;
    }
}

// ---------- GAT aggregation: aggregate x (12ch), project through Wg per node ----------
__global__ void __launch_bounds__(256) k_agg(
    const void* __restrict__ xraw, const float* __restrict__ WgG,
    const float* __restrict__ a_s, const float* __restrict__ a_d,
    const int* __restrict__ offs, const int* __restrict__ deg,
    const int* __restrict__ ssrc, const float* __restrict__ bias,
    const int* __restrict__ flags, float* __restrict__ gT) {
    __shared__ float swg[1152];
    __shared__ float sres[4][12];
    int tid = threadIdx.x, wave = tid >> 6, lane = tid & 63;
    for (int i = tid; i < 1152; i += 256) swg[i] = WgG[i];
    __syncthreads();
    int node = blockIdx.x * 4 + wave;
    int beg = offs[node], d = deg[node];
    int sub = lane >> 3, h = lane & 7;
    float adh = a_d[node * 8 + h];
    int bf = flags[0];
    float acc[12];
    float wsum = 0.f;
#pragma unroll
    for (int c = 0; c < 12; c++) acc[c] = 0.f;
    if (sub == 0) {
        float w = __expf(lrelu(a_s[node * 8 + h] + adh));
        wsum = w;
        if (bf) {
            const uint2* xp = (const uint2*)((const uint16_t*)xraw + node * 12);
            uint2 u0 = xp[0], u1 = xp[1], u2 = xp[2];
            acc[0] = w * bflo(u0.x); acc[1] = w * bfhi(u0.x);
            acc[2] = w * bflo(u0.y); acc[3] = w * bfhi(u0.y);
            acc[4] = w * bflo(u1.x); acc[5] = w * bfhi(u1.x);
            acc[6] = w * bflo(u1.y); acc[7] = w * bfhi(u1.y);
            acc[8] = w * bflo(u2.x); acc[9] = w * bfhi(u2.x);
            acc[10] = w * bflo(u2.y); acc[11] = w * bfhi(u2.y);
        } else {
            const float4* xp = (const float4*)((const float*)xraw + node * 12);
            float4 v0 = xp[0], v1 = xp[1], v2 = xp[2];
            acc[0] = w * v0.x; acc[1] = w * v0.y; acc[2] = w * v0.z; acc[3] = w * v0.w;
            acc[4] = w * v1.x; acc[5] = w * v1.y; acc[6] = w * v1.z; acc[7] = w * v1.w;
            acc[8] = w * v2.x; acc[9] = w * v2.y; acc[10] = w * v2.z; acc[11] = w * v2.w;
        }
    }
    for (int base = 0; base < d; base += 8) {
        int k = base + sub;
        if (k < d) {
            int s = ssrc[beg + k];
            float w = __expf(lrelu(a_s[s * 8 + h] + adh));
            wsum += w;
            if (bf) {
                const uint2* xp = (const uint2*)((const uint16_t*)xraw + s * 12);
                uint2 u0 = xp[0], u1 = xp[1], u2 = xp[2];
                acc[0] += w * bflo(u0.x); acc[1] += w * bfhi(u0.x);
                acc[2] += w * bflo(u0.y); acc[3] += w * bfhi(u0.y);
                acc[4] += w * bflo(u1.x); acc[5] += w * bfhi(u1.x);
                acc[6] += w * bflo(u1.y); acc[7] += w * bfhi(u1.y);
                acc[8] += w * bflo(u2.x); acc[9] += w * bfhi(u2.x);
                acc[10] += w * bflo(u2.y); acc[11] += w * bfhi(u2.y);
            } else {
                const float4* xp = (const float4*)((const float*)xraw + s * 12);
                float4 v0 = xp[0], v1 = xp[1], v2 = xp[2];
                acc[0] += w * v0.x; acc[1] += w * v0.y; acc[2] += w * v0.z; acc[3] += w * v0.w;
                acc[4] += w * v1.x; acc[5] += w * v1.y; acc[6] += w * v1.z; acc[7] += w * v1.w;
                acc[8] += w * v2.x; acc[9] += w * v2.y; acc[10] += w * v2.z; acc[11] += w * v2.w;
            }
        }
    }
#pragma unroll
    for (int off = 8; off <= 32; off <<= 1) {
        wsum += __shfl_xor(wsum, off, 64);
#pragma unroll
        for (int c = 0; c < 12; c++) acc[c] += __shfl_xor(acc[c], off, 64);
    }
    float invw = 1.f / wsum;
#pragma unroll
    for (int c = 0; c < 12; c++) acc[c] *= invw;
    float p0 = 0.f, p1 = 0.f;
    const float* wcol = swg + h * 12;
#pragma unroll
    for (int k = 0; k < 12; k++) {
        float a = acc[k];
        p0 += a * wcol[k * 96 + sub];
        p1 += a * wcol[k * 96 + sub + 4];
    }
#pragma unroll
    for (int off = 1; off <= 4; off <<= 1) {
        p0 += __shfl_xor(p0, off, 64);
        p1 += __shfl_xor(p1, off, 64);
    }
    if (h == 0) {
        sres[wave][sub] = p0;
        if (sub >= 4) sres[wave][sub + 4] = p1;
    }
    __syncthreads();
    if (tid < 48) {
        int no = tid / 12, c = tid % 12;
        gT[c * NTOT + blockIdx.x * 4 + no] = sres[no][c] * 0.125f + bias[c];
    }
}

// ---------- Z1: 4 batches per block, weight loads shared ----------
__global__ void __launch_bounds__(256) k_z1(const float* __restrict__ gT,
                                            const void* __restrict__ Wraw,
                                            const float* __restrict__ b1,
                                            const float* __restrict__ b2,
                                            const int* __restrict__ flags,
                                            float* __restrict__ Z1) {
    int t = blockIdx.x >> 3, bg = (blockIdx.x & 7) * 4;
    __shared__ float sv[4][2048];
    __shared__ float zp[2][4][128];
    int tid = threadIdx.x;
#pragma unroll
    for (int q = 0; q < 4; q++)
        for (int v = tid; v < 2048; v += 256) sv[q][v] = gT[t * NTOT + (bg + q) * NNODE + v];
    __syncthreads();
    int row = tid & 127, half = tid >> 7;
    float a0 = 0.f, a1 = 0.f, a2 = 0.f, a3 = 0.f;
    int hbase = half * 1024;
    if (flags[0]) {
        const uint4* wp = (const uint4*)((const uint16_t*)Wraw + row * 2048 + hbase);
        for (int k = 0; k < 128; k++) {
            uint4 u = wp[k];
            float w0 = bflo(u.x), w1 = bfhi(u.x), w2 = bflo(u.y), w3 = bfhi(u.y);
            float w4 = bflo(u.z), w5 = bfhi(u.z), w6 = bflo(u.w), w7 = bfhi(u.w);
#pragma unroll
            for (int q = 0; q < 4; q++) {
                float4 A = *(const float4*)&sv[q][hbase + 8 * k];
                float4 B = *(const float4*)&sv[q][hbase + 8 * k + 4];
                float r = w0 * A.x + w1 * A.y + w2 * A.z + w3 * A.w
                        + w4 * B.x + w5 * B.y + w6 * B.z + w7 * B.w;
                if (q == 0) a0 += r; else if (q == 1) a1 += r;
                else if (q == 2) a2 += r; else a3 += r;
            }
        }
    } else {
        const float4* wp = (const float4*)((const float*)Wraw + row * 2048 + hbase);
        for (int k = 0; k < 256; k++) {
            float4 w = wp[k];
#pragma unroll
            for (int q = 0; q < 4; q++) {
                float4 A = *(const float4*)&sv[q][hbase + 4 * k];
                float r = w.x * A.x + w.y * A.y + w.z * A.z + w.w * A.w;
                if (q == 0) a0 += r; else if (q == 1) a1 += r;
                else if (q == 2) a2 += r; else a3 += r;
            }
        }
    }
    zp[half][0][row] = a0; zp[half][1][row] = a1;
    zp[half][2][row] = a2; zp[half][3][row] = a3;
    __syncthreads();
    if (tid < 128) {
        float bb = b1[tid] + b2[tid];
#pragma unroll
        for (int q = 0; q < 4; q++)
            Z1[t * 4096 + (bg + q) * 128 + tid] = zp[0][q][tid] + zp[1][q][tid] + bb;
    }
}

// ---------- fused tail: LSTM1 + Wih2 proj + LSTM2 ----------
// 512 threads = 8 waves; lane = kh*32 + gp*16 + (e&15), e = wave*16 + (lane&15).
// Key change this round: the 12-step t-loops are NOT unrolled (#pragma unroll 1)
// so the loop bodies stay I$-resident and are reused 12x (the fully-unrolled
// ~50-100KB straight-line body was streaming through the I-cache with zero
// reuse -- the ~100us fixed cost). z-inputs go through small LDS arrays
// (zsA/zsB) instead of runtime-indexed register arrays (rule #20).
__global__ void __launch_bounds__(512, 2) k_tail(
    const float* __restrict__ Z1,
    const void* __restrict__ Whh1r,
    const void* __restrict__ Wih2r, const void* __restrict__ Whh2r,
    const float* __restrict__ b2i, const float* __restrict__ b2h,
    const int* __restrict__ flags, float* __restrict__ h2l) {
    int b = blockIdx.x, tid = threadIdx.x;
    __shared__ __align__(16) float h1s[12 * 32];
    __shared__ __align__(16) float hb1[32];
    __shared__ __align__(16) float hb[2][128];
    __shared__ float zsA[12 * 512];
    __shared__ float zsB[12 * 512];
    int bf = flags[0];
    int lane = tid & 63, wv = tid >> 6;
    int kh = lane >> 5;            // K-half
    int gp = (lane >> 4) & 1;      // gate pair: 0 -> (i,f), 1 -> (g,o)
    int e = wv * 16 + (lane & 15); // element 0..127
    int rA = gp * 256 + e;         // row of gate i (or g)
    int rB = gp * 256 + 128 + e;   // row of gate f (or o)

    // ---- Phase B: LSTM1 recurrence on wave 0 (zero barriers) ----
    if (tid < 64) {
        int l = tid;
        float wA[32], wB[32];
        if (bf) {
            const uint32_t* w1 = (const uint32_t*)Whh1r;
#pragma unroll
            for (int k = 0; k < 16; k++) {
                uint32_t u = w1[l * 16 + k];
                wA[2 * k] = bflo(u); wA[2 * k + 1] = bfhi(u);
                uint32_t v = w1[(l + 64) * 16 + k];
                wB[2 * k] = bflo(v); wB[2 * k + 1] = bfhi(v);
            }
        } else {
            const float* w1 = (const float*)Whh1r;
#pragma unroll
            for (int k = 0; k < 32; k++) {
                wA[k] = w1[l * 32 + k];
                wB[k] = w1[(l + 64) * 32 + k];
            }
        }
        if (l < 32) hb1[l] = 0.f;
        __threadfence_block();
        float c = 0.f;
        float d0 = Z1[b * 128 + l];
        float d1 = Z1[b * 128 + 64 + l];
#pragma unroll 1
        for (int t = 0; t < 12; t++) {
            float n0 = 0.f, n1 = 0.f;
            if (t < 11) {   // prefetch next step's z (hides L2 latency)
                n0 = Z1[(t + 1) * 4096 + b * 128 + l];
                n1 = Z1[(t + 1) * 4096 + b * 128 + 64 + l];
            }
#pragma unroll
            for (int k = 0; k < 8; k++) {
                float4 h4 = *(const float4*)&hb1[4 * k];
                d0 += wA[4*k]*h4.x + wA[4*k+1]*h4.y + wA[4*k+2]*h4.z + wA[4*k+3]*h4.w;
                d1 += wB[4*k]*h4.x + wB[4*k+1]*h4.y + wB[4*k+2]*h4.z + wB[4*k+3]*h4.w;
            }
            float e0 = __shfl_xor(d0, 32, 64);
            float e1 = __shfl_xor(d1, 32, 64);
            if (l < 32) {
                c = sigmf(e0) * c + sigmf(d0) * tanhfast(d1);
                float h = sigmf(e1) * tanhfast(c);
                hb1[l] = h;
                h1s[t * 32 + l] = h;
            }
            __threadfence_block();
            d0 = n0; d1 = n1;
        }
    }

    // ---- pin weights (waves 1..7 overlap these loads with Phase B) ----
    float zbA = b2i[rA] + b2h[rA];
    float zbB = b2i[rB] + b2h[rB];
    uint4 wdA[8], wdB[8];   // Whh2 rows rA,rB, K-half kh (64 bf16 each)
    uint4 wiA[4], wiB[4];   // Wih2 rows rA,rB (32 bf16 each)
    if (bf) {
        const uint16_t* W2 = (const uint16_t*)Whh2r;
        const uint4* pA = (const uint4*)(W2 + rA * 128 + kh * 64);
        const uint4* pB = (const uint4*)(W2 + rB * 128 + kh * 64);
#pragma unroll
        for (int k = 0; k < 8; k++) { wdA[k] = pA[k]; wdB[k] = pB[k]; }
        const uint4* qA = (const uint4*)((const uint16_t*)Wih2r + rA * 32);
        const uint4* qB = (const uint4*)((const uint16_t*)Wih2r + rB * 32);
#pragma unroll
        for (int k = 0; k < 4; k++) { wiA[k] = qA[k]; wiB[k] = qB[k]; }
    }
    if (tid < 128) hb[0][tid] = 0.f;
    __syncthreads();

    // ---- Phase C: Wih2 projection -> zsA/zsB LDS (rows rA,rB, all 12 t) ----
    if (bf) {
#pragma unroll 1
        for (int t = 0; t < 12; t++) {
            const float4* hp = (const float4*)&h1s[t * 32];
            float a = zbA, c = zbB;
#pragma unroll
            for (int k = 0; k < 4; k++) {
                float4 h0 = hp[2 * k], h1 = hp[2 * k + 1];
                uint4 ua = wiA[k], ub = wiB[k];
                a += bflo(ua.x)*h0.x + bfhi(ua.x)*h0.y + bflo(ua.y)*h0.z + bfhi(ua.y)*h0.w
                   + bflo(ua.z)*h1.x + bfhi(ua.z)*h1.y + bflo(ua.w)*h1.z + bfhi(ua.w)*h1.w;
                c += bflo(ub.x)*h0.x + bfhi(ub.x)*h0.y + bflo(ub.y)*h0.z + bfhi(ub.y)*h0.w
                   + bflo(ub.z)*h1.x + bfhi(ub.z)*h1.y + bflo(ub.w)*h1.z + bfhi(ub.w)*h1.w;
            }
            zsA[t * 512 + tid] = a; zsB[t * 512 + tid] = c;
        }
    } else {
        const float* Wi = (const float*)Wih2r;
        const float4* qA = (const float4*)(Wi + rA * 32);
        const float4* qB = (const float4*)(Wi + rB * 32);
#pragma unroll 1
        for (int t = 0; t < 12; t++) {
            const float4* hp = (const float4*)&h1s[t * 32];
            float a = zbA, c = zbB;
#pragma unroll
            for (int k = 0; k < 8; k++) {
                float4 h4 = hp[k];
                float4 qa = qA[k], qb = qB[k];
                a += qa.x*h4.x + qa.y*h4.y + qa.z*h4.z + qa.w*h4.w;
                c += qb.x*h4.x + qb.y*h4.y + qb.z*h4.z + qb.w*h4.w;
            }
            zsA[t * 512 + tid] = a; zsB[t * 512 + tid] = c;
        }
    }

    // ---- Phase D: LSTM2 recurrence, 1 barrier/step, shfl gate exchange ----
    const float* W2f = (const float*)Whh2r;
    const float4* wfA = (const float4*)(W2f + rA * 128 + kh * 64);
    const float4* wfB = (const float4*)(W2f + rB * 128 + kh * 64);
    float c2 = 0.f;
#pragma unroll 1
    for (int t = 0; t < 12; t++) {
        const float4* hp = (const float4*)&hb[t & 1][kh * 64];
        float pA = 0.f, pB = 0.f;
        if (kh == 0) { pA = zsA[t * 512 + tid]; pB = zsB[t * 512 + tid]; }
        if (bf) {
#pragma unroll
            for (int k = 0; k < 8; k++) {
                float4 ha = hp[2 * k], hc = hp[2 * k + 1];
                uint4 ua = wdA[k], ub = wdB[k];
                pA += bflo(ua.x)*ha.x + bfhi(ua.x)*ha.y + bflo(ua.y)*ha.z + bfhi(ua.y)*ha.w
                    + bflo(ua.z)*hc.x + bfhi(ua.z)*hc.y + bflo(ua.w)*hc.z + bfhi(ua.w)*hc.w;
                pB += bflo(ub.x)*ha.x + bfhi(ub.x)*ha.y + bflo(ub.y)*ha.z + bfhi(ub.y)*ha.w
                    + bflo(ub.z)*hc.x + bfhi(ub.z)*hc.y + bflo(ub.w)*hc.z + bfhi(ub.w)*hc.w;
            }
        } else {
#pragma unroll
            for (int k = 0; k < 16; k++) {
                float4 h4 = hp[k];
                float4 qa = wfA[k], qb = wfB[k];
                pA += qa.x*h4.x + qa.y*h4.y + qa.z*h4.z + qa.w*h4.w;
                pB += qb.x*h4.x + qb.y*h4.y + qb.z*h4.z + qb.w*h4.w;
            }
        }
        // cross-half sum (lane ^ 32): both halves hold full z for rows rA,rB
        float zA = pA + __shfl_xor(pA, 32, 64);
        float zB = pB + __shfl_xor(pB, 32, 64);
        // gate exchange (lane ^ 16): gp0 lanes receive (g,o) from gp1 partner
        float zg_ = __shfl_xor(zA, 16, 64);
        float zo_ = __shfl_xor(zB, 16, 64);
        if (gp == 0) {
            c2 = sigmf(zB) * c2 + sigmf(zA) * tanhfast(zg_);
            float hh = sigmf(zo_) * tanhfast(c2);
            if (kh == 0) {
                hb[(t & 1) ^ 1][e] = hh;
                if (t == 11) h2l[b * 128 + e] = hh;
            }
        }
        __syncthreads();
    }
}

// ---------- final linear (dual-path W) ----------
__global__ void __launch_bounds__(256) k_lin(const float* __restrict__ h2l,
                                             const void* __restrict__ Wraw,
                                             const float* __restrict__ bl,
                                             const int* __restrict__ flags,
                                             void* __restrict__ outv) {
    __shared__ float hl[8 * 128];
    int bg = blockIdx.y;
    for (int i = threadIdx.x; i < 1024; i += 256) hl[i] = h2l[bg * 1024 + i];
    __syncthreads();
    int o = blockIdx.x * 256 + threadIdx.x;
    float bb = bl[o];
    float acc[8];
#pragma unroll
    for (int b = 0; b < 8; b++) acc[b] = bb;
    int bf = flags[0];
    if (bf) {
        const uint4* wp = (const uint4*)((const uint16_t*)Wraw + o * 128);
        for (int k = 0; k < 16; k++) {
            uint4 u = wp[k];
            float w0 = bflo(u.x), w1 = bfhi(u.x), w2 = bflo(u.y), w3 = bfhi(u.y);
            float w4 = bflo(u.z), w5 = bfhi(u.z), w6 = bflo(u.w), w7 = bfhi(u.w);
#pragma unroll
            for (int b = 0; b < 8; b++) {
                const float* h8 = hl + b * 128 + k * 8;
                acc[b] += w0 * h8[0] + w1 * h8[1] + w2 * h8[2] + w3 * h8[3]
                        + w4 * h8[4] + w5 * h8[5] + w6 * h8[6] + w7 * h8[7];
            }
        }
    } else {
        const float4* wp = (const float4*)((const float*)Wraw + o * 128);
        for (int k = 0; k < 32; k++) {
            float4 w = wp[k];
#pragma unroll
            for (int b = 0; b < 8; b++) {
                const float* h4 = hl + b * 128 + k * 4;
                acc[b] += w.x * h4[0] + w.y * h4[1] + w.z * h4[2] + w.w * h4[3];
            }
        }
    }
    if (bf) {
        uint16_t* out = (uint16_t*)outv;
#pragma unroll
        for (int b = 0; b < 8; b++) out[(bg * 8 + b) * 18432 + o] = f2bf(acc[b]);
    } else {
        float* out = (float*)outv;
#pragma unroll
        for (int b = 0; b < 8; b++) out[(bg * 8 + b) * 18432 + o] = acc[b];
    }
}

extern "C" void kernel_launch(void* const* d_in, const int* in_sizes, int n_in,
                              void* d_out, int out_size, void* d_ws, size_t ws_size,
                              hipStream_t stream) {
    int E = in_sizes[1] / 2;

    float* ws = (float*)d_ws;
    int* flags = (int*)ws;          // [0]=bf16 [1]=stride [2]=gcount
    float* cWg   = ws + O_WG;
    float* cAtt  = ws + O_AS;
    float* cBias = ws + O_BIAS;
    float* cBih1 = ws + O_BIH1;
    float* cBhh1 = ws + O_BHH1;
    float* cBih2 = ws + O_BIH2;
    float* cBhh2 = ws + O_BHH2;
    float* cBlin = ws + O_BLIN;

    float* base = ws + O_END;
    float* a_s  = base;                            // 524288
    float* a_d  = a_s + 524288;                    // 524288
    int* deg    = (int*)(a_d + 524288);            // 65536
    int* offs   = deg + 65536;                     // 65536
    int* rank   = offs + 65536;                    // E
    int* ssrc   = rank + E;                        // E
    float* gT   = (float*)(ssrc + E);              // 786432
    float* Z1   = gT + 786432;                     // 49152
    float* h2l  = Z1 + 49152;                      // 4096
    size_t needed = (size_t)((h2l + 4096) - ws) * 4;
    if (ws_size < needed) return;

    k_pre<<<256, 256, 0, stream>>>(d_in[0], (const int*)d_in[1],
                                   d_in[2], d_in[3], d_in[4], d_in[5],
                                   d_in[8], d_in[9], d_in[12], d_in[13], d_in[15],
                                   ws, deg);
    k_nfa<<<2048, 256, 0, stream>>>(d_in[0], cWg, cAtt, flags,
                                    (const int*)d_in[1], E, deg, rank,
                                    a_s, a_d);
    k_scan<<<256, 256, 0, stream>>>(deg, offs, flags + 2);
    k_scatter<<<(E + 255) / 256, 256, 0, stream>>>((const int*)d_in[1], E, flags,
                                                   offs, rank, ssrc);
    k_agg<<<NTOT / 4, 256, 0, stream>>>(d_in[0], cWg, a_s, a_d, offs, deg, ssrc,
                                        cBias, flags, gT);
    k_z1<<<96, 256, 0, stream>>>(gT, d_in[6], cBih1, cBhh1, flags, Z1);
    k_tail<<<32, 512, 0, stream>>>(Z1, d_in[7], d_in[10], d_in[11],
                                   cBih2, cBhh2, flags, h2l);
    k_lin<<<dim3(72, 4), 256, 0, stream>>>(h2l, d_in[14], cBlin, flags, d_out);
}

// Round 4
// 316.483 us; speedup vs baseline: 1.4209x; 1.2073x over previous
//
#include <hip/hip_runtime.h>
#include <hip/hip_bf16.h>
#include <stdint.h>

#define NTOT 65536   // B * N_NODE
#define NNODE 2048
#define CIN 12

__device__ __forceinline__ float bf2f(uint32_t u) {
    union { uint32_t i; float f; } v; v.i = u << 16; return v.f;
}
__device__ __forceinline__ uint16_t f2bf(float f) {
    union { float f; uint32_t i; } v; v.f = f;
    uint32_t x = v.i;
    uint32_t r = x + 0x7fffu + ((x >> 16) & 1u);
    return (uint16_t)(r >> 16);
}
__device__ __forceinline__ float bflo(uint32_t u) { return bf2f(u & 0xffffu); }
__device__ __forceinline__ float bfhi(uint32_t u) { return bf2f(u >> 16); }
__device__ __forceinline__ float sigmf(float x) {
    return __builtin_amdgcn_rcpf(1.0f + __expf(-x));
}
__device__ __forceinline__ float tanhfast(float x) {
    float ex = __expf(2.0f * x);
    return 1.0f - 2.0f * __builtin_amdgcn_rcpf(ex + 1.0f);
}
__device__ __forceinline__ float lrelu(float v) { return v > 0.f ? v : 0.2f * v; }

// ws float offsets (flags[0]=bf16?, flags[1]=edge stride words, flags[2]=gcount)
#define O_WG   16
#define O_AS   1168
#define O_AD   1264
#define O_BIAS 1360
#define O_BIH1 1376
#define O_BHH1 1504
#define O_BIH2 1632
#define O_BHH2 2144
#define O_BLIN 2656
#define O_END  21088

__device__ __forceinline__ void cvt(const void* s, float* d, int i, int bf) {
    d[i] = bf ? bf2f(((const uint16_t*)s)[i]) : ((const float*)s)[i];
}

// ---------- fused: dtype detect + small-tensor conv + zero ----------
__global__ void __launch_bounds__(256) k_pre(
    const void* x, const int* __restrict__ e32,
    const void* wg, const void* as_, const void* ad_, const void* bs,
    const void* b1, const void* bb1, const void* b2, const void* bb2,
    const void* bl, float* __restrict__ ws, int* __restrict__ deg) {
    int tid = threadIdx.x, lane = tid & 63;
    uint32_t u = ((const uint16_t*)x)[2 * lane];
    uint32_t ex = (u >> 7) & 0xFF;
    bool sane = (ex >= 0x60 && ex <= 0x9F) || (u == 0);
    unsigned long long bsx = __ballot(sane);
    bool hi_zero = (e32[2 * lane + 1] == 0);
    unsigned long long bz = __ballot(hi_zero);
    int bf = (__popcll(bsx) >= 52) ? 1 : 0;
    int st = (__popcll(bz) == 64) ? 2 : 1;
    if (blockIdx.x == 0 && tid == 0) {
        ((int*)ws)[0] = bf; ((int*)ws)[1] = st; ((int*)ws)[2] = 0;
    }
    deg[blockIdx.x * 256 + tid] = 0;
    int i = blockIdx.x * 256 + tid;
    if (i < 1152)  { cvt(wg,  ws + O_WG,   i, bf); return; } i -= 1152;
    if (i < 96)    { cvt(as_, ws + O_AS,   i, bf); return; } i -= 96;
    if (i < 96)    { cvt(ad_, ws + O_AD,   i, bf); return; } i -= 96;
    if (i < 12)    { cvt(bs,  ws + O_BIAS, i, bf); return; } i -= 12;
    if (i < 128)   { cvt(b1,  ws + O_BIH1, i, bf); return; } i -= 128;
    if (i < 128)   { cvt(bb1, ws + O_BHH1, i, bf); return; } i -= 128;
    if (i < 512)   { cvt(b2,  ws + O_BIH2, i, bf); return; } i -= 512;
    if (i < 512)   { cvt(bb2, ws + O_BHH2, i, bf); return; } i -= 512;
    if (i < 18432) { cvt(bl,  ws + O_BLIN, i, bf); }
}

// ---------- fused attention scores + edge histogram ----------
__global__ void __launch_bounds__(256) k_nfa(const void* __restrict__ xraw,
                                             const float* __restrict__ Wg,
                                             const float* __restrict__ att,
                                             const int* __restrict__ flags,
                                             const int* __restrict__ e, int E,
                                             int* __restrict__ deg, int* __restrict__ rank,
                                             float* __restrict__ a_s, float* __restrict__ a_d) {
    __shared__ float sx[384];
    __shared__ float sw[1152];
    __shared__ float satt[192];
    __shared__ float sh[3072];
    int tid = threadIdx.x;
    int n0 = blockIdx.x * 32;
    if (flags[0]) {
        const uint32_t* xp = (const uint32_t*)xraw;
        for (int i = tid; i < 192; i += 256) {
            uint32_t u = xp[n0 * 6 + i];
            sx[2 * i] = bflo(u); sx[2 * i + 1] = bfhi(u);
        }
    } else {
        const float* xp = (const float*)xraw;
        for (int i = tid; i < 384; i += 256) sx[i] = xp[n0 * 12 + i];
    }
    for (int i = tid; i < 1152; i += 256) sw[i] = Wg[i];
    if (tid < 192) satt[tid] = att[tid];
    {
        long st = flags[1];
        int chunk = (E + gridDim.x - 1) / gridDim.x;
        int ebase = blockIdx.x * chunk;
        int eend = min(ebase + chunk, E);
        for (int i = ebase + tid; i < eend; i += 256) {
            int d = e[st * (E + i)];
            rank[i] = atomicAdd(&deg[d], 1);
        }
    }
    __syncthreads();
#pragma unroll
    for (int r = 0; r < 12; r++) {
        int idx = r * 256 + tid;
        int n = idx / 96, o = idx % 96;
        float acc = 0.f;
#pragma unroll
        for (int k = 0; k < 12; k++) acc += sx[n * 12 + k] * sw[k * 96 + o];
        sh[idx] = acc;
    }
    __syncthreads();
    {
        int nl = tid >> 3, h = tid & 7;
        const float* hr = sh + nl * 96 + h * 12;
        float s = 0.f, dd = 0.f;
#pragma unroll
        for (int c = 0; c < 12; c++) {
            float v = hr[c];
            s += v * satt[h * 12 + c];
            dd += v * satt[96 + h * 12 + c];
        }
        a_s[n0 * 8 + tid] = s;
        a_d[n0 * 8 + tid] = dd;
    }
}

// ---------- scan: local exclusive scan + atomic global base ----------
__global__ void k_scan(const int* __restrict__ deg, int* __restrict__ offs,
                       int* __restrict__ gcount) {
    __shared__ int s[256];
    __shared__ int base;
    int t = threadIdx.x, i = blockIdx.x * 256 + t;
    int v = deg[i];
    s[t] = v; __syncthreads();
    for (int off = 1; off < 256; off <<= 1) {
        int a = (t >= off) ? s[t - off] : 0;
        __syncthreads();
        s[t] += a;
        __syncthreads();
    }
    if (t == 255) base = atomicAdd(gcount, s[255]);
    __syncthreads();
    offs[i] = base + s[t] - v;
}

__global__ void k_scatter(const int* __restrict__ e, int E, const int* __restrict__ flags,
                          const int* __restrict__ offs, const int* __restrict__ rank,
                          int* __restrict__ ssrc) {
    int i = blockIdx.x * 256 + threadIdx.x;
    if (i < E) {
        long st = flags[1];
        int s = e[st * i];
        int d = e[st * (E + i)];
        ssrc[offs[d] + rank[i]] = s;
    }
}

// ---------- GAT aggregation: aggregate x (12ch), project through Wg per node ----------
__global__ void __launch_bounds__(256) k_agg(
    const void* __restrict__ xraw, const float* __restrict__ WgG,
    const float* __restrict__ a_s, const float* __restrict__ a_d,
    const int* __restrict__ offs, const int* __restrict__ deg,
    const int* __restrict__ ssrc, const float* __restrict__ bias,
    const int* __restrict__ flags, float* __restrict__ gT) {
    __shared__ float swg[1152];
    __shared__ float sres[4][12];
    int tid = threadIdx.x, wave = tid >> 6, lane = tid & 63;
    for (int i = tid; i < 1152; i += 256) swg[i] = WgG[i];
    __syncthreads();
    int node = blockIdx.x * 4 + wave;
    int beg = offs[node], d = deg[node];
    int sub = lane >> 3, h = lane & 7;
    float adh = a_d[node * 8 + h];
    int bf = flags[0];
    float acc[12];
    float wsum = 0.f;
#pragma unroll
    for (int c = 0; c < 12; c++) acc[c] = 0.f;
    if (sub == 0) {
        float w = __expf(lrelu(a_s[node * 8 + h] + adh));
        wsum = w;
        if (bf) {
            const uint2* xp = (const uint2*)((const uint16_t*)xraw + node * 12);
            uint2 u0 = xp[0], u1 = xp[1], u2 = xp[2];
            acc[0] = w * bflo(u0.x); acc[1] = w * bfhi(u0.x);
            acc[2] = w * bflo(u0.y); acc[3] = w * bfhi(u0.y);
            acc[4] = w * bflo(u1.x); acc[5] = w * bfhi(u1.x);
            acc[6] = w * bflo(u1.y); acc[7] = w * bfhi(u1.y);
            acc[8] = w * bflo(u2.x); acc[9] = w * bfhi(u2.x);
            acc[10] = w * bflo(u2.y); acc[11] = w * bfhi(u2.y);
        } else {
            const float4* xp = (const float4*)((const float*)xraw + node * 12);
            float4 v0 = xp[0], v1 = xp[1], v2 = xp[2];
            acc[0] = w * v0.x; acc[1] = w * v0.y; acc[2] = w * v0.z; acc[3] = w * v0.w;
            acc[4] = w * v1.x; acc[5] = w * v1.y; acc[6] = w * v1.z; acc[7] = w * v1.w;
            acc[8] = w * v2.x; acc[9] = w * v2.y; acc[10] = w * v2.z; acc[11] = w * v2.w;
        }
    }
    for (int base = 0; base < d; base += 8) {
        int k = base + sub;
        if (k < d) {
            int s = ssrc[beg + k];
            float w = __expf(lrelu(a_s[s * 8 + h] + adh));
            wsum += w;
            if (bf) {
                const uint2* xp = (const uint2*)((const uint16_t*)xraw + s * 12);
                uint2 u0 = xp[0], u1 = xp[1], u2 = xp[2];
                acc[0] += w * bflo(u0.x); acc[1] += w * bfhi(u0.x);
                acc[2] += w * bflo(u0.y); acc[3] += w * bfhi(u0.y);
                acc[4] += w * bflo(u1.x); acc[5] += w * bfhi(u1.x);
                acc[6] += w * bflo(u1.y); acc[7] += w * bfhi(u1.y);
                acc[8] += w * bflo(u2.x); acc[9] += w * bfhi(u2.x);
                acc[10] += w * bflo(u2.y); acc[11] += w * bfhi(u2.y);
            } else {
                const float4* xp = (const float4*)((const float*)xraw + s * 12);
                float4 v0 = xp[0], v1 = xp[1], v2 = xp[2];
                acc[0] += w * v0.x; acc[1] += w * v0.y; acc[2] += w * v0.z; acc[3] += w * v0.w;
                acc[4] += w * v1.x; acc[5] += w * v1.y; acc[6] += w * v1.z; acc[7] += w * v1.w;
                acc[8] += w * v2.x; acc[9] += w * v2.y; acc[10] += w * v2.z; acc[11] += w * v2.w;
            }
        }
    }
#pragma unroll
    for (int off = 8; off <= 32; off <<= 1) {
        wsum += __shfl_xor(wsum, off, 64);
#pragma unroll
        for (int c = 0; c < 12; c++) acc[c] += __shfl_xor(acc[c], off, 64);
    }
    float invw = 1.f / wsum;
#pragma unroll
    for (int c = 0; c < 12; c++) acc[c] *= invw;
    float p0 = 0.f, p1 = 0.f;
    const float* wcol = swg + h * 12;
#pragma unroll
    for (int k = 0; k < 12; k++) {
        float a = acc[k];
        p0 += a * wcol[k * 96 + sub];
        p1 += a * wcol[k * 96 + sub + 4];
    }
#pragma unroll
    for (int off = 1; off <= 4; off <<= 1) {
        p0 += __shfl_xor(p0, off, 64);
        p1 += __shfl_xor(p1, off, 64);
    }
    if (h == 0) {
        sres[wave][sub] = p0;
        if (sub >= 4) sres[wave][sub + 4] = p1;
    }
    __syncthreads();
    if (tid < 48) {
        int no = tid / 12, c = tid % 12;
        gT[c * NTOT + blockIdx.x * 4 + no] = sres[no][c] * 0.125f + bias[c];
    }
}

// ---------- Z1: 4 batches per block, weight loads shared ----------
__global__ void __launch_bounds__(256) k_z1(const float* __restrict__ gT,
                                            const void* __restrict__ Wraw,
                                            const float* __restrict__ b1,
                                            const float* __restrict__ b2,
                                            const int* __restrict__ flags,
                                            float* __restrict__ Z1) {
    int t = blockIdx.x >> 3, bg = (blockIdx.x & 7) * 4;
    __shared__ float sv[4][2048];
    __shared__ float zp[2][4][128];
    int tid = threadIdx.x;
#pragma unroll
    for (int q = 0; q < 4; q++)
        for (int v = tid; v < 2048; v += 256) sv[q][v] = gT[t * NTOT + (bg + q) * NNODE + v];
    __syncthreads();
    int row = tid & 127, half = tid >> 7;
    float a0 = 0.f, a1 = 0.f, a2 = 0.f, a3 = 0.f;
    int hbase = half * 1024;
    if (flags[0]) {
        const uint4* wp = (const uint4*)((const uint16_t*)Wraw + row * 2048 + hbase);
        for (int k = 0; k < 128; k++) {
            uint4 u = wp[k];
            float w0 = bflo(u.x), w1 = bfhi(u.x), w2 = bflo(u.y), w3 = bfhi(u.y);
            float w4 = bflo(u.z), w5 = bfhi(u.z), w6 = bflo(u.w), w7 = bfhi(u.w);
#pragma unroll
            for (int q = 0; q < 4; q++) {
                float4 A = *(const float4*)&sv[q][hbase + 8 * k];
                float4 B = *(const float4*)&sv[q][hbase + 8 * k + 4];
                float r = w0 * A.x + w1 * A.y + w2 * A.z + w3 * A.w
                        + w4 * B.x + w5 * B.y + w6 * B.z + w7 * B.w;
                if (q == 0) a0 += r; else if (q == 1) a1 += r;
                else if (q == 2) a2 += r; else a3 += r;
            }
        }
    } else {
        const float4* wp = (const float4*)((const float*)Wraw + row * 2048 + hbase);
        for (int k = 0; k < 256; k++) {
            float4 w = wp[k];
#pragma unroll
            for (int q = 0; q < 4; q++) {
                float4 A = *(const float4*)&sv[q][hbase + 4 * k];
                float r = w.x * A.x + w.y * A.y + w.z * A.z + w.w * A.w;
                if (q == 0) a0 += r; else if (q == 1) a1 += r;
                else if (q == 2) a2 += r; else a3 += r;
            }
        }
    }
    zp[half][0][row] = a0; zp[half][1][row] = a1;
    zp[half][2][row] = a2; zp[half][3][row] = a3;
    __syncthreads();
    if (tid < 128) {
        float bb = b1[tid] + b2[tid];
#pragma unroll
        for (int q = 0; q < 4; q++)
            Z1[t * 4096 + (bg + q) * 128 + tid] = zp[0][q][tid] + zp[1][q][tid] + bb;
    }
}

// ---------- LSTM1: one block (64 thr) per batch, fully unrolled ----------
__global__ void __launch_bounds__(64) k_lstm1(
    const float* __restrict__ Z1, const void* __restrict__ Whh1r,
    const int* __restrict__ flags, float* __restrict__ h1g) {
    int b = blockIdx.x, l = threadIdx.x;
    __shared__ __align__(16) float hb1[32];
    int bf = flags[0];
    float wA[32], wB[32];
    if (bf) {
        const uint32_t* w1 = (const uint32_t*)Whh1r;
#pragma unroll
        for (int k = 0; k < 16; k++) {
            uint32_t u = w1[l * 16 + k];
            wA[2 * k] = bflo(u); wA[2 * k + 1] = bfhi(u);
            uint32_t v = w1[(l + 64) * 16 + k];
            wB[2 * k] = bflo(v); wB[2 * k + 1] = bfhi(v);
        }
    } else {
        const float* w1 = (const float*)Whh1r;
#pragma unroll
        for (int k = 0; k < 32; k++) {
            wA[k] = w1[l * 32 + k];
            wB[k] = w1[(l + 64) * 32 + k];
        }
    }
    float za[12], zg[12];
#pragma unroll
    for (int t = 0; t < 12; t++) {
        za[t] = Z1[t * 4096 + b * 128 + l];
        zg[t] = Z1[t * 4096 + b * 128 + 64 + l];
    }
    if (l < 32) hb1[l] = 0.f;
    __builtin_amdgcn_wave_barrier();
    float c = 0.f;
#pragma unroll
    for (int t = 0; t < 12; t++) {
        float d0 = za[t], d1 = zg[t];
#pragma unroll
        for (int k = 0; k < 8; k++) {
            float4 h4 = *(const float4*)&hb1[4 * k];
            d0 += wA[4*k]*h4.x + wA[4*k+1]*h4.y + wA[4*k+2]*h4.z + wA[4*k+3]*h4.w;
            d1 += wB[4*k]*h4.x + wB[4*k+1]*h4.y + wB[4*k+2]*h4.z + wB[4*k+3]*h4.w;
        }
        float e0 = __shfl_xor(d0, 32, 64);
        float e1 = __shfl_xor(d1, 32, 64);
        if (l < 32) {
            c = sigmf(e0) * c + sigmf(d0) * tanhfast(d1);
            float h = sigmf(e1) * tanhfast(c);
            hb1[l] = h;
            h1g[t * 1024 + b * 32 + l] = h;
        }
        __builtin_amdgcn_wave_barrier();
    }
}

// ---------- Wih2 projection: t-parallel, one row per thread ----------
__global__ void __launch_bounds__(512) k_wih2(
    const float* __restrict__ h1g, const void* __restrict__ Wih2r,
    const float* __restrict__ b2i, const float* __restrict__ b2h,
    const int* __restrict__ flags, float* __restrict__ z2g) {
    int tb = blockIdx.x;              // t*32 + b
    int t = tb >> 5, b = tb & 31;
    int r = threadIdx.x;              // 0..511
    __shared__ __align__(16) float h[32];
    if (r < 32) h[r] = h1g[t * 1024 + b * 32 + r];
    __syncthreads();
    float z = b2i[r] + b2h[r];
    const float4* hp = (const float4*)h;
    if (flags[0]) {
        const uint4* wp = (const uint4*)((const uint16_t*)Wih2r + r * 32);
#pragma unroll
        for (int k = 0; k < 4; k++) {
            uint4 u = wp[k];
            float4 h0 = hp[2 * k], h1 = hp[2 * k + 1];
            z += bflo(u.x)*h0.x + bfhi(u.x)*h0.y + bflo(u.y)*h0.z + bfhi(u.y)*h0.w
               + bflo(u.z)*h1.x + bfhi(u.z)*h1.y + bflo(u.w)*h1.z + bfhi(u.w)*h1.w;
        }
    } else {
        const float4* wp = (const float4*)((const float*)Wih2r + r * 32);
#pragma unroll
        for (int k = 0; k < 8; k++) {
            float4 w = wp[k];
            float4 h4 = hp[k];
            z += w.x*h4.x + w.y*h4.y + w.z*h4.z + w.w*h4.w;
        }
    }
    z2g[t * 16384 + b * 512 + r] = z;
}

// ---------- LSTM2: one block (512 thr) per batch, f32-pinned weights ----------
// lane = kh*32 + gp*16 + (e&15); e = wave*16 + (lane&15).
// Thread computes 2 row-partials (rA=gate i/g, rB=gate f/o) over its 64-wide
// K-half with pre-unpacked f32 weights in 128 VGPRs. Cross-half sum via
// shfl_xor(32), gate exchange via shfl_xor(16). One barrier per step.
__global__ void __launch_bounds__(512, 1) k_lstm2(
    const float* __restrict__ z2g, const void* __restrict__ Whh2r,
    const int* __restrict__ flags, float* __restrict__ h2l) {
    int b = blockIdx.x, tid = threadIdx.x;
    __shared__ __align__(16) float hb[2][128];
    int bf = flags[0];
    int lane = tid & 63, wv = tid >> 6;
    int kh = lane >> 5;
    int gp = (lane >> 4) & 1;
    int e = wv * 16 + (lane & 15);
    int rA = gp * 256 + e;
    int rB = gp * 256 + 128 + e;

    float wA[64], wB[64];
    if (bf) {
        const uint16_t* W2 = (const uint16_t*)Whh2r;
        const uint4* pA = (const uint4*)(W2 + rA * 128 + kh * 64);
        const uint4* pB = (const uint4*)(W2 + rB * 128 + kh * 64);
#pragma unroll
        for (int k = 0; k < 8; k++) {
            uint4 ua = pA[k], ub = pB[k];
            wA[8*k+0] = bflo(ua.x); wA[8*k+1] = bfhi(ua.x);
            wA[8*k+2] = bflo(ua.y); wA[8*k+3] = bfhi(ua.y);
            wA[8*k+4] = bflo(ua.z); wA[8*k+5] = bfhi(ua.z);
            wA[8*k+6] = bflo(ua.w); wA[8*k+7] = bfhi(ua.w);
            wB[8*k+0] = bflo(ub.x); wB[8*k+1] = bfhi(ub.x);
            wB[8*k+2] = bflo(ub.y); wB[8*k+3] = bfhi(ub.y);
            wB[8*k+4] = bflo(ub.z); wB[8*k+5] = bfhi(ub.z);
            wB[8*k+6] = bflo(ub.w); wB[8*k+7] = bfhi(ub.w);
        }
    } else {
        const float4* pA = (const float4*)((const float*)Whh2r + rA * 128 + kh * 64);
        const float4* pB = (const float4*)((const float*)Whh2r + rB * 128 + kh * 64);
#pragma unroll
        for (int k = 0; k < 16; k++) {
            float4 a = pA[k], c = pB[k];
            wA[4*k+0] = a.x; wA[4*k+1] = a.y; wA[4*k+2] = a.z; wA[4*k+3] = a.w;
            wB[4*k+0] = c.x; wB[4*k+1] = c.y; wB[4*k+2] = c.z; wB[4*k+3] = c.w;
        }
    }
    if (tid < 128) hb[0][tid] = 0.f;
    const float* zb = z2g + b * 512;
    float zA = 0.f, zB = 0.f;
    if (kh == 0) { zA = zb[rA]; zB = zb[rB]; }
    float c2 = 0.f;
    __syncthreads();
#pragma unroll 1
    for (int t = 0; t < 12; t++) {
        float nA = 0.f, nB = 0.f;
        if (t < 11 && kh == 0) {       // prefetch next step's z (L2-hit)
            nA = zb[(t + 1) * 16384 + rA];
            nB = zb[(t + 1) * 16384 + rB];
        }
        const float4* hp = (const float4*)&hb[t & 1][kh * 64];
        float pA = zA, pB = zB;
#pragma unroll
        for (int k = 0; k < 16; k++) {
            float4 h4 = hp[k];
            pA += wA[4*k]*h4.x + wA[4*k+1]*h4.y + wA[4*k+2]*h4.z + wA[4*k+3]*h4.w;
            pB += wB[4*k]*h4.x + wB[4*k+1]*h4.y + wB[4*k+2]*h4.z + wB[4*k+3]*h4.w;
        }
        // cross-half sum (lane ^ 32): both halves hold full z for rows rA,rB
        float sA = pA + __shfl_xor(pA, 32, 64);
        float sB = pB + __shfl_xor(pB, 32, 64);
        // gate exchange (lane ^ 16): gp0 lanes receive (g,o) from gp1 partner
        float zg_ = __shfl_xor(sA, 16, 64);
        float zo_ = __shfl_xor(sB, 16, 64);
        if (gp == 0) {
            c2 = sigmf(sB) * c2 + sigmf(sA) * tanhfast(zg_);
            float hh = sigmf(zo_) * tanhfast(c2);
            if (kh == 0) {
                hb[(t & 1) ^ 1][e] = hh;
                if (t == 11) h2l[b * 128 + e] = hh;
            }
        }
        __syncthreads();
        zA = nA; zB = nB;
    }
}

// ---------- final linear (dual-path W) ----------
__global__ void __launch_bounds__(256) k_lin(const float* __restrict__ h2l,
                                             const void* __restrict__ Wraw,
                                             const float* __restrict__ bl,
                                             const int* __restrict__ flags,
                                             void* __restrict__ outv) {
    __shared__ float hl[8 * 128];
    int bg = blockIdx.y;
    for (int i = threadIdx.x; i < 1024; i += 256) hl[i] = h2l[bg * 1024 + i];
    __syncthreads();
    int o = blockIdx.x * 256 + threadIdx.x;
    float bb = bl[o];
    float acc[8];
#pragma unroll
    for (int b = 0; b < 8; b++) acc[b] = bb;
    int bf = flags[0];
    if (bf) {
        const uint4* wp = (const uint4*)((const uint16_t*)Wraw + o * 128);
        for (int k = 0; k < 16; k++) {
            uint4 u = wp[k];
            float w0 = bflo(u.x), w1 = bfhi(u.x), w2 = bflo(u.y), w3 = bfhi(u.y);
            float w4 = bflo(u.z), w5 = bfhi(u.z), w6 = bflo(u.w), w7 = bfhi(u.w);
#pragma unroll
            for (int b = 0; b < 8; b++) {
                const float* h8 = hl + b * 128 + k * 8;
                acc[b] += w0 * h8[0] + w1 * h8[1] + w2 * h8[2] + w3 * h8[3]
                        + w4 * h8[4] + w5 * h8[5] + w6 * h8[6] + w7 * h8[7];
            }
        }
    } else {
        const float4* wp = (const float4*)((const float*)Wraw + o * 128);
        for (int k = 0; k < 32; k++) {
            float4 w = wp[k];
#pragma unroll
            for (int b = 0; b < 8; b++) {
                const float* h4 = hl + b * 128 + k * 4;
                acc[b] += w.x * h4[0] + w.y * h4[1] + w.z * h4[2] + w.w * h4[3];
            }
        }
    }
    if (bf) {
        uint16_t* out = (uint16_t*)outv;
#pragma unroll
        for (int b = 0; b < 8; b++) out[(bg * 8 + b) * 18432 + o] = f2bf(acc[b]);
    } else {
        float* out = (float*)outv;
#pragma unroll
        for (int b = 0; b < 8; b++) out[(bg * 8 + b) * 18432 + o] = acc[b];
    }
}

extern "C" void kernel_launch(void* const* d_in, const int* in_sizes, int n_in,
                              void* d_out, int out_size, void* d_ws, size_t ws_size,
                              hipStream_t stream) {
    int E = in_sizes[1] / 2;

    float* ws = (float*)d_ws;
    int* flags = (int*)ws;          // [0]=bf16 [1]=stride [2]=gcount
    float* cWg   = ws + O_WG;
    float* cAtt  = ws + O_AS;
    float* cBias = ws + O_BIAS;
    float* cBih1 = ws + O_BIH1;
    float* cBhh1 = ws + O_BHH1;
    float* cBih2 = ws + O_BIH2;
    float* cBhh2 = ws + O_BHH2;
    float* cBlin = ws + O_BLIN;

    float* base = ws + O_END;
    float* a_s  = base;                            // 524288
    float* a_d  = a_s + 524288;                    // 524288
    int* deg    = (int*)(a_d + 524288);            // 65536
    int* offs   = deg + 65536;                     // 65536
    int* rank   = offs + 65536;                    // E
    int* ssrc   = rank + E;                        // E
    float* gT   = (float*)(ssrc + E);              // 786432
    float* Z1   = gT + 786432;                     // 49152
    float* h2l  = Z1 + 49152;                      // 4096
    float* h1g  = h2l + 4096;                      // 12288  (12*32*32)
    float* z2g  = h1g + 12288;                     // 196608 (12*32*512)
    size_t needed = (size_t)((z2g + 196608) - ws) * 4;
    if (ws_size < needed) return;

    k_pre<<<256, 256, 0, stream>>>(d_in[0], (const int*)d_in[1],
                                   d_in[2], d_in[3], d_in[4], d_in[5],
                                   d_in[8], d_in[9], d_in[12], d_in[13], d_in[15],
                                   ws, deg);
    k_nfa<<<2048, 256, 0, stream>>>(d_in[0], cWg, cAtt, flags,
                                    (const int*)d_in[1], E, deg, rank,
                                    a_s, a_d);
    k_scan<<<256, 256, 0, stream>>>(deg, offs, flags + 2);
    k_scatter<<<(E + 255) / 256, 256, 0, stream>>>((const int*)d_in[1], E, flags,
                                                   offs, rank, ssrc);
    k_agg<<<NTOT / 4, 256, 0, stream>>>(d_in[0], cWg, a_s, a_d, offs, deg, ssrc,
                                        cBias, flags, gT);
    k_z1<<<96, 256, 0, stream>>>(gT, d_in[6], cBih1, cBhh1, flags, Z1);
    k_lstm1<<<32, 64, 0, stream>>>(Z1, d_in[7], flags, h1g);
    k_wih2<<<384, 512, 0, stream>>>(h1g, d_in[10], cBih2, cBhh2, flags, z2g);
    k_lstm2<<<32, 512, 0, stream>>>(z2g, d_in[11], flags, h2l);
    k_lin<<<dim3(72, 4), 256, 0, stream>>>(h2l, d_in[14], cBlin, flags, d_out);
}

// Round 5
// 306.953 us; speedup vs baseline: 1.4650x; 1.0310x over previous
//
#include <hip/hip_runtime.h>
#include <hip/hip_bf16.h>
#include <stdint.h>

#define NTOT 65536   // B * N_NODE
#define NNODE 2048
#define CIN 12

__device__ __forceinline__ float bf2f(uint32_t u) {
    union { uint32_t i; float f; } v; v.i = u << 16; return v.f;
}
__device__ __forceinline__ uint16_t f2bf(float f) {
    union { float f; uint32_t i; } v; v.f = f;
    uint32_t x = v.i;
    uint32_t r = x + 0x7fffu + ((x >> 16) & 1u);
    return (uint16_t)(r >> 16);
}
__device__ __forceinline__ float bflo(uint32_t u) { return bf2f(u & 0xffffu); }
__device__ __forceinline__ float bfhi(uint32_t u) { return bf2f(u >> 16); }
__device__ __forceinline__ float sigmf(float x) {
    return __builtin_amdgcn_rcpf(1.0f + __expf(-x));
}
__device__ __forceinline__ float tanhfast(float x) {
    float ex = __expf(2.0f * x);
    return 1.0f - 2.0f * __builtin_amdgcn_rcpf(ex + 1.0f);
}
__device__ __forceinline__ float lrelu(float v) { return v > 0.f ? v : 0.2f * v; }

// ws float offsets (flags[0]=bf16?, flags[1]=edge stride words, flags[2]=gcount)
#define O_WG   16
#define O_AS   1168
#define O_AD   1264
#define O_BIAS 1360
#define O_BIH1 1376
#define O_BHH1 1504
#define O_BIH2 1632
#define O_BHH2 2144
#define O_BLIN 2656
#define O_END  21088

__device__ __forceinline__ void cvt(const void* s, float* d, int i, int bf) {
    d[i] = bf ? bf2f(((const uint16_t*)s)[i]) : ((const float*)s)[i];
}

// ---------- fused: dtype detect + small-tensor conv + zero ----------
__global__ void __launch_bounds__(256) k_pre(
    const void* x, const int* __restrict__ e32,
    const void* wg, const void* as_, const void* ad_, const void* bs,
    const void* b1, const void* bb1, const void* b2, const void* bb2,
    const void* bl, float* __restrict__ ws, int* __restrict__ deg) {
    int tid = threadIdx.x, lane = tid & 63;
    uint32_t u = ((const uint16_t*)x)[2 * lane];
    uint32_t ex = (u >> 7) & 0xFF;
    bool sane = (ex >= 0x60 && ex <= 0x9F) || (u == 0);
    unsigned long long bsx = __ballot(sane);
    bool hi_zero = (e32[2 * lane + 1] == 0);
    unsigned long long bz = __ballot(hi_zero);
    int bf = (__popcll(bsx) >= 52) ? 1 : 0;
    int st = (__popcll(bz) == 64) ? 2 : 1;
    if (blockIdx.x == 0 && tid == 0) {
        ((int*)ws)[0] = bf; ((int*)ws)[1] = st; ((int*)ws)[2] = 0;
    }
    deg[blockIdx.x * 256 + tid] = 0;
    int i = blockIdx.x * 256 + tid;
    if (i < 1152)  { cvt(wg,  ws + O_WG,   i, bf); return; } i -= 1152;
    if (i < 96)    { cvt(as_, ws + O_AS,   i, bf); return; } i -= 96;
    if (i < 96)    { cvt(ad_, ws + O_AD,   i, bf); return; } i -= 96;
    if (i < 12)    { cvt(bs,  ws + O_BIAS, i, bf); return; } i -= 12;
    if (i < 128)   { cvt(b1,  ws + O_BIH1, i, bf); return; } i -= 128;
    if (i < 128)   { cvt(bb1, ws + O_BHH1, i, bf); return; } i -= 128;
    if (i < 512)   { cvt(b2,  ws + O_BIH2, i, bf); return; } i -= 512;
    if (i < 512)   { cvt(bb2, ws + O_BHH2, i, bf); return; } i -= 512;
    if (i < 18432) { cvt(bl,  ws + O_BLIN, i, bf); }
}

// ---------- fused attention scores + edge histogram + packed node record ----------
// bf path writes rec[n] (64 B): [a_s[n][0..7] f32 | x[n][0..11] bf16 | pad]
// so k_agg's per-edge gather touches ONE cacheline instead of two.
__global__ void __launch_bounds__(256) k_nfa(const void* __restrict__ xraw,
                                             const float* __restrict__ Wg,
                                             const float* __restrict__ att,
                                             const int* __restrict__ flags,
                                             const int* __restrict__ e, int E,
                                             int* __restrict__ deg, int* __restrict__ rank,
                                             float* __restrict__ a_s, float* __restrict__ a_d,
                                             float* __restrict__ rec) {
    __shared__ float sx[384];
    __shared__ float sw[1152];
    __shared__ float satt[192];
    __shared__ float sh[3072];
    int tid = threadIdx.x;
    int n0 = blockIdx.x * 32;
    int bf = flags[0];
    if (bf) {
        const uint32_t* xp = (const uint32_t*)xraw;
        uint32_t* rx = (uint32_t*)rec;
        for (int i = tid; i < 192; i += 256) {
            uint32_t u = xp[n0 * 6 + i];
            sx[2 * i] = bflo(u); sx[2 * i + 1] = bfhi(u);
            rx[(size_t)(n0 + i / 6) * 16 + 8 + i % 6] = u;  // pack x into record
        }
    } else {
        const float* xp = (const float*)xraw;
        for (int i = tid; i < 384; i += 256) sx[i] = xp[n0 * 12 + i];
    }
    for (int i = tid; i < 1152; i += 256) sw[i] = Wg[i];
    if (tid < 192) satt[tid] = att[tid];
    {
        long st = flags[1];
        int chunk = (E + gridDim.x - 1) / gridDim.x;
        int ebase = blockIdx.x * chunk;
        int eend = min(ebase + chunk, E);
        for (int i = ebase + tid; i < eend; i += 256) {
            int d = e[st * (E + i)];
            rank[i] = atomicAdd(&deg[d], 1);
        }
    }
    __syncthreads();
#pragma unroll
    for (int r = 0; r < 12; r++) {
        int idx = r * 256 + tid;
        int n = idx / 96, o = idx % 96;
        float acc = 0.f;
#pragma unroll
        for (int k = 0; k < 12; k++) acc += sx[n * 12 + k] * sw[k * 96 + o];
        sh[idx] = acc;
    }
    __syncthreads();
    {
        int nl = tid >> 3, h = tid & 7;
        const float* hr = sh + nl * 96 + h * 12;
        float s = 0.f, dd = 0.f;
#pragma unroll
        for (int c = 0; c < 12; c++) {
            float v = hr[c];
            s += v * satt[h * 12 + c];
            dd += v * satt[96 + h * 12 + c];
        }
        if (bf) rec[(size_t)(n0 + nl) * 16 + h] = s;   // score into record
        else    a_s[n0 * 8 + tid] = s;
        a_d[n0 * 8 + tid] = dd;
    }
}

// ---------- scan: local exclusive scan + atomic global base ----------
__global__ void k_scan(const int* __restrict__ deg, int* __restrict__ offs,
                       int* __restrict__ gcount) {
    __shared__ int s[256];
    __shared__ int base;
    int t = threadIdx.x, i = blockIdx.x * 256 + t;
    int v = deg[i];
    s[t] = v; __syncthreads();
    for (int off = 1; off < 256; off <<= 1) {
        int a = (t >= off) ? s[t - off] : 0;
        __syncthreads();
        s[t] += a;
        __syncthreads();
    }
    if (t == 255) base = atomicAdd(gcount, s[255]);
    __syncthreads();
    offs[i] = base + s[t] - v;
}

__global__ void k_scatter(const int* __restrict__ e, int E, const int* __restrict__ flags,
                          const int* __restrict__ offs, const int* __restrict__ rank,
                          int* __restrict__ ssrc) {
    int i = blockIdx.x * 256 + threadIdx.x;
    if (i < E) {
        long st = flags[1];
        int s = e[st * i];
        int d = e[st * (E + i)];
        ssrc[offs[d] + rank[i]] = s;
    }
}

// ---------- GAT aggregation: one-line-per-edge packed gather (bf16 path) ----------
__global__ void __launch_bounds__(256) k_agg(
    const void* __restrict__ xraw, const float* __restrict__ WgG,
    const float* __restrict__ a_s, const float* __restrict__ a_d,
    const int* __restrict__ offs, const int* __restrict__ deg,
    const int* __restrict__ ssrc, const float* __restrict__ bias,
    const int* __restrict__ flags, const float* __restrict__ rec,
    float* __restrict__ gT) {
    __shared__ float swg[1152];
    __shared__ float sres[4][12];
    int tid = threadIdx.x, wave = tid >> 6, lane = tid & 63;
    for (int i = tid; i < 1152; i += 256) swg[i] = WgG[i];
    __syncthreads();
    int node = blockIdx.x * 4 + wave;
    int beg = offs[node], d = deg[node];
    int sub = lane >> 3, h = lane & 7;
    float adh = a_d[node * 8 + h];
    int bf = flags[0];
    float acc[12];
    float wsum = 0.f;
#pragma unroll
    for (int c = 0; c < 12; c++) acc[c] = 0.f;
    if (bf) {
        // self loop from packed record
        if (sub == 0) {
            const float* rp0 = rec + (size_t)node * 16;
            float asv = rp0[h];
            float w = __expf(lrelu(asv + adh));
            wsum = w;
            uint4 xu = *(const uint4*)(rp0 + 8);
            uint2 xv = *(const uint2*)(rp0 + 12);
            acc[0] = w * bflo(xu.x); acc[1] = w * bfhi(xu.x);
            acc[2] = w * bflo(xu.y); acc[3] = w * bfhi(xu.y);
            acc[4] = w * bflo(xu.z); acc[5] = w * bfhi(xu.z);
            acc[6] = w * bflo(xu.w); acc[7] = w * bfhi(xu.w);
            acc[8] = w * bflo(xv.x); acc[9] = w * bfhi(xv.x);
            acc[10] = w * bflo(xv.y); acc[11] = w * bfhi(xv.y);
        }
        if (d > 0) {
            // software-pipelined one-line gathers; invalid lanes masked w=0
            int k = sub;
            int s0 = ssrc[beg + min(k, d - 1)];
            const float* rp = rec + (size_t)s0 * 16;
            float asv = rp[h];
            uint4 xu = *(const uint4*)(rp + 8);
            uint2 xv = *(const uint2*)(rp + 12);
            for (int base = 0; base < d; base += 8, k += 8) {
                int kn = k + 8;
                int s1 = (kn < d) ? ssrc[beg + kn] : s0;
                const float* rpn = rec + (size_t)s1 * 16;
                float asv_n = rpn[h];
                uint4 xu_n = *(const uint4*)(rpn + 8);
                uint2 xv_n = *(const uint2*)(rpn + 12);
                float w = __expf(lrelu(asv + adh));
                if (k >= d) w = 0.f;
                wsum += w;
                acc[0] += w * bflo(xu.x); acc[1] += w * bfhi(xu.x);
                acc[2] += w * bflo(xu.y); acc[3] += w * bfhi(xu.y);
                acc[4] += w * bflo(xu.z); acc[5] += w * bfhi(xu.z);
                acc[6] += w * bflo(xu.w); acc[7] += w * bfhi(xu.w);
                acc[8] += w * bflo(xv.x); acc[9] += w * bfhi(xv.x);
                acc[10] += w * bflo(xv.y); acc[11] += w * bfhi(xv.y);
                asv = asv_n; xu = xu_n; xv = xv_n; s0 = s1;
            }
        }
    } else {
        // legacy f32 path
        if (sub == 0) {
            float w = __expf(lrelu(a_s[node * 8 + h] + adh));
            wsum = w;
            const float4* xp = (const float4*)((const float*)xraw + node * 12);
            float4 v0 = xp[0], v1 = xp[1], v2 = xp[2];
            acc[0] = w * v0.x; acc[1] = w * v0.y; acc[2] = w * v0.z; acc[3] = w * v0.w;
            acc[4] = w * v1.x; acc[5] = w * v1.y; acc[6] = w * v1.z; acc[7] = w * v1.w;
            acc[8] = w * v2.x; acc[9] = w * v2.y; acc[10] = w * v2.z; acc[11] = w * v2.w;
        }
        for (int base = 0; base < d; base += 8) {
            int k = base + sub;
            if (k < d) {
                int s = ssrc[beg + k];
                float w = __expf(lrelu(a_s[s * 8 + h] + adh));
                wsum += w;
                const float4* xp = (const float4*)((const float*)xraw + s * 12);
                float4 v0 = xp[0], v1 = xp[1], v2 = xp[2];
                acc[0] += w * v0.x; acc[1] += w * v0.y; acc[2] += w * v0.z; acc[3] += w * v0.w;
                acc[4] += w * v1.x; acc[5] += w * v1.y; acc[6] += w * v1.z; acc[7] += w * v1.w;
                acc[8] += w * v2.x; acc[9] += w * v2.y; acc[10] += w * v2.z; acc[11] += w * v2.w;
            }
        }
    }
#pragma unroll
    for (int off = 8; off <= 32; off <<= 1) {
        wsum += __shfl_xor(wsum, off, 64);
#pragma unroll
        for (int c = 0; c < 12; c++) acc[c] += __shfl_xor(acc[c], off, 64);
    }
    float invw = 1.f / wsum;
#pragma unroll
    for (int c = 0; c < 12; c++) acc[c] *= invw;
    float p0 = 0.f, p1 = 0.f;
    const float* wcol = swg + h * 12;
#pragma unroll
    for (int k = 0; k < 12; k++) {
        float a = acc[k];
        p0 += a * wcol[k * 96 + sub];
        p1 += a * wcol[k * 96 + sub + 4];
    }
#pragma unroll
    for (int off = 1; off <= 4; off <<= 1) {
        p0 += __shfl_xor(p0, off, 64);
        p1 += __shfl_xor(p1, off, 64);
    }
    if (h == 0) {
        sres[wave][sub] = p0;
        if (sub >= 4) sres[wave][sub + 4] = p1;
    }
    __syncthreads();
    if (tid < 48) {
        int no = tid / 12, c = tid % 12;
        gT[c * NTOT + blockIdx.x * 4 + no] = sres[no][c] * 0.125f + bias[c];
    }
}

// ---------- Z1: 4 batches per block, weight loads shared ----------
__global__ void __launch_bounds__(256) k_z1(const float* __restrict__ gT,
                                            const void* __restrict__ Wraw,
                                            const float* __restrict__ b1,
                                            const float* __restrict__ b2,
                                            const int* __restrict__ flags,
                                            float* __restrict__ Z1) {
    int t = blockIdx.x >> 3, bg = (blockIdx.x & 7) * 4;
    __shared__ float sv[4][2048];
    __shared__ float zp[2][4][128];
    int tid = threadIdx.x;
#pragma unroll
    for (int q = 0; q < 4; q++)
        for (int v = tid; v < 2048; v += 256) sv[q][v] = gT[t * NTOT + (bg + q) * NNODE + v];
    __syncthreads();
    int row = tid & 127, half = tid >> 7;
    float a0 = 0.f, a1 = 0.f, a2 = 0.f, a3 = 0.f;
    int hbase = half * 1024;
    if (flags[0]) {
        const uint4* wp = (const uint4*)((const uint16_t*)Wraw + row * 2048 + hbase);
        for (int k = 0; k < 128; k++) {
            uint4 u = wp[k];
            float w0 = bflo(u.x), w1 = bfhi(u.x), w2 = bflo(u.y), w3 = bfhi(u.y);
            float w4 = bflo(u.z), w5 = bfhi(u.z), w6 = bflo(u.w), w7 = bfhi(u.w);
#pragma unroll
            for (int q = 0; q < 4; q++) {
                float4 A = *(const float4*)&sv[q][hbase + 8 * k];
                float4 B = *(const float4*)&sv[q][hbase + 8 * k + 4];
                float r = w0 * A.x + w1 * A.y + w2 * A.z + w3 * A.w
                        + w4 * B.x + w5 * B.y + w6 * B.z + w7 * B.w;
                if (q == 0) a0 += r; else if (q == 1) a1 += r;
                else if (q == 2) a2 += r; else a3 += r;
            }
        }
    } else {
        const float4* wp = (const float4*)((const float*)Wraw + row * 2048 + hbase);
        for (int k = 0; k < 256; k++) {
            float4 w = wp[k];
#pragma unroll
            for (int q = 0; q < 4; q++) {
                float4 A = *(const float4*)&sv[q][hbase + 4 * k];
                float r = w.x * A.x + w.y * A.y + w.z * A.z + w.w * A.w;
                if (q == 0) a0 += r; else if (q == 1) a1 += r;
                else if (q == 2) a2 += r; else a3 += r;
            }
        }
    }
    zp[half][0][row] = a0; zp[half][1][row] = a1;
    zp[half][2][row] = a2; zp[half][3][row] = a3;
    __syncthreads();
    if (tid < 128) {
        float bb = b1[tid] + b2[tid];
#pragma unroll
        for (int q = 0; q < 4; q++)
            Z1[t * 4096 + (bg + q) * 128 + tid] = zp[0][q][tid] + zp[1][q][tid] + bb;
    }
}

// ---------- LSTM1: one block (64 thr) per batch, fully unrolled ----------
__global__ void __launch_bounds__(64) k_lstm1(
    const float* __restrict__ Z1, const void* __restrict__ Whh1r,
    const int* __restrict__ flags, float* __restrict__ h1g) {
    int b = blockIdx.x, l = threadIdx.x;
    __shared__ __align__(16) float hb1[32];
    int bf = flags[0];
    float wA[32], wB[32];
    if (bf) {
        const uint32_t* w1 = (const uint32_t*)Whh1r;
#pragma unroll
        for (int k = 0; k < 16; k++) {
            uint32_t u = w1[l * 16 + k];
            wA[2 * k] = bflo(u); wA[2 * k + 1] = bfhi(u);
            uint32_t v = w1[(l + 64) * 16 + k];
            wB[2 * k] = bflo(v); wB[2 * k + 1] = bfhi(v);
        }
    } else {
        const float* w1 = (const float*)Whh1r;
#pragma unroll
        for (int k = 0; k < 32; k++) {
            wA[k] = w1[l * 32 + k];
            wB[k] = w1[(l + 64) * 32 + k];
        }
    }
    float za[12], zg[12];
#pragma unroll
    for (int t = 0; t < 12; t++) {
        za[t] = Z1[t * 4096 + b * 128 + l];
        zg[t] = Z1[t * 4096 + b * 128 + 64 + l];
    }
    if (l < 32) hb1[l] = 0.f;
    __builtin_amdgcn_wave_barrier();
    float c = 0.f;
#pragma unroll
    for (int t = 0; t < 12; t++) {
        float d0 = za[t], d1 = zg[t];
#pragma unroll
        for (int k = 0; k < 8; k++) {
            float4 h4 = *(const float4*)&hb1[4 * k];
            d0 += wA[4*k]*h4.x + wA[4*k+1]*h4.y + wA[4*k+2]*h4.z + wA[4*k+3]*h4.w;
            d1 += wB[4*k]*h4.x + wB[4*k+1]*h4.y + wB[4*k+2]*h4.z + wB[4*k+3]*h4.w;
        }
        float e0 = __shfl_xor(d0, 32, 64);
        float e1 = __shfl_xor(d1, 32, 64);
        if (l < 32) {
            c = sigmf(e0) * c + sigmf(d0) * tanhfast(d1);
            float h = sigmf(e1) * tanhfast(c);
            hb1[l] = h;
            h1g[t * 1024 + b * 32 + l] = h;
        }
        __builtin_amdgcn_wave_barrier();
    }
}

// ---------- Wih2 projection: t-parallel, one row per thread ----------
__global__ void __launch_bounds__(512) k_wih2(
    const float* __restrict__ h1g, const void* __restrict__ Wih2r,
    const float* __restrict__ b2i, const float* __restrict__ b2h,
    const int* __restrict__ flags, float* __restrict__ z2g) {
    int tb = blockIdx.x;              // t*32 + b
    int t = tb >> 5, b = tb & 31;
    int r = threadIdx.x;              // 0..511
    __shared__ __align__(16) float h[32];
    if (r < 32) h[r] = h1g[t * 1024 + b * 32 + r];
    __syncthreads();
    float z = b2i[r] + b2h[r];
    const float4* hp = (const float4*)h;
    if (flags[0]) {
        const uint4* wp = (const uint4*)((const uint16_t*)Wih2r + r * 32);
#pragma unroll
        for (int k = 0; k < 4; k++) {
            uint4 u = wp[k];
            float4 h0 = hp[2 * k], h1 = hp[2 * k + 1];
            z += bflo(u.x)*h0.x + bfhi(u.x)*h0.y + bflo(u.y)*h0.z + bfhi(u.y)*h0.w
               + bflo(u.z)*h1.x + bfhi(u.z)*h1.y + bflo(u.w)*h1.z + bfhi(u.w)*h1.w;
        }
    } else {
        const float4* wp = (const float4*)((const float*)Wih2r + r * 32);
#pragma unroll
        for (int k = 0; k < 8; k++) {
            float4 w = wp[k];
            float4 h4 = hp[k];
            z += w.x*h4.x + w.y*h4.y + w.z*h4.z + w.w*h4.w;
        }
    }
    z2g[t * 16384 + b * 512 + r] = z;
}

// ---------- LSTM2: one block (512 thr) per batch, f32-pinned weights ----------
__global__ void __launch_bounds__(512, 1) k_lstm2(
    const float* __restrict__ z2g, const void* __restrict__ Whh2r,
    const int* __restrict__ flags, float* __restrict__ h2l) {
    int b = blockIdx.x, tid = threadIdx.x;
    __shared__ __align__(16) float hb[2][128];
    int bf = flags[0];
    int lane = tid & 63, wv = tid >> 6;
    int kh = lane >> 5;
    int gp = (lane >> 4) & 1;
    int e = wv * 16 + (lane & 15);
    int rA = gp * 256 + e;
    int rB = gp * 256 + 128 + e;

    float wA[64], wB[64];
    if (bf) {
        const uint16_t* W2 = (const uint16_t*)Whh2r;
        const uint4* pA = (const uint4*)(W2 + rA * 128 + kh * 64);
        const uint4* pB = (const uint4*)(W2 + rB * 128 + kh * 64);
#pragma unroll
        for (int k = 0; k < 8; k++) {
            uint4 ua = pA[k], ub = pB[k];
            wA[8*k+0] = bflo(ua.x); wA[8*k+1] = bfhi(ua.x);
            wA[8*k+2] = bflo(ua.y); wA[8*k+3] = bfhi(ua.y);
            wA[8*k+4] = bflo(ua.z); wA[8*k+5] = bfhi(ua.z);
            wA[8*k+6] = bflo(ua.w); wA[8*k+7] = bfhi(ua.w);
            wB[8*k+0] = bflo(ub.x); wB[8*k+1] = bfhi(ub.x);
            wB[8*k+2] = bflo(ub.y); wB[8*k+3] = bfhi(ub.y);
            wB[8*k+4] = bflo(ub.z); wB[8*k+5] = bfhi(ub.z);
            wB[8*k+6] = bflo(ub.w); wB[8*k+7] = bfhi(ub.w);
        }
    } else {
        const float4* pA = (const float4*)((const float*)Whh2r + rA * 128 + kh * 64);
        const float4* pB = (const float4*)((const float*)Whh2r + rB * 128 + kh * 64);
#pragma unroll
        for (int k = 0; k < 16; k++) {
            float4 a = pA[k], c = pB[k];
            wA[4*k+0] = a.x; wA[4*k+1] = a.y; wA[4*k+2] = a.z; wA[4*k+3] = a.w;
            wB[4*k+0] = c.x; wB[4*k+1] = c.y; wB[4*k+2] = c.z; wB[4*k+3] = c.w;
        }
    }
    if (tid < 128) hb[0][tid] = 0.f;
    const float* zb = z2g + b * 512;
    float zA = 0.f, zB = 0.f;
    if (kh == 0) { zA = zb[rA]; zB = zb[rB]; }
    float c2 = 0.f;
    __syncthreads();
#pragma unroll 1
    for (int t = 0; t < 12; t++) {
        float nA = 0.f, nB = 0.f;
        if (t < 11 && kh == 0) {       // prefetch next step's z (L2-hit)
            nA = zb[(t + 1) * 16384 + rA];
            nB = zb[(t + 1) * 16384 + rB];
        }
        const float4* hp = (const float4*)&hb[t & 1][kh * 64];
        float pA = zA, pB = zB;
#pragma unroll
        for (int k = 0; k < 16; k++) {
            float4 h4 = hp[k];
            pA += wA[4*k]*h4.x + wA[4*k+1]*h4.y + wA[4*k+2]*h4.z + wA[4*k+3]*h4.w;
            pB += wB[4*k]*h4.x + wB[4*k+1]*h4.y + wB[4*k+2]*h4.z + wB[4*k+3]*h4.w;
        }
        float sA = pA + __shfl_xor(pA, 32, 64);
        float sB = pB + __shfl_xor(pB, 32, 64);
        float zg_ = __shfl_xor(sA, 16, 64);
        float zo_ = __shfl_xor(sB, 16, 64);
        if (gp == 0) {
            c2 = sigmf(sB) * c2 + sigmf(sA) * tanhfast(zg_);
            float hh = sigmf(zo_) * tanhfast(c2);
            if (kh == 0) {
                hb[(t & 1) ^ 1][e] = hh;
                if (t == 11) h2l[b * 128 + e] = hh;
            }
        }
        __syncthreads();
        zA = nA; zB = nB;
    }
}

// ---------- final linear (dual-path W) ----------
__global__ void __launch_bounds__(256) k_lin(const float* __restrict__ h2l,
                                             const void* __restrict__ Wraw,
                                             const float* __restrict__ bl,
                                             const int* __restrict__ flags,
                                             void* __restrict__ outv) {
    __shared__ float hl[8 * 128];
    int bg = blockIdx.y;
    for (int i = threadIdx.x; i < 1024; i += 256) hl[i] = h2l[bg * 1024 + i];
    __syncthreads();
    int o = blockIdx.x * 256 + threadIdx.x;
    float bb = bl[o];
    float acc[8];
#pragma unroll
    for (int b = 0; b < 8; b++) acc[b] = bb;
    int bf = flags[0];
    if (bf) {
        const uint4* wp = (const uint4*)((const uint16_t*)Wraw + o * 128);
        for (int k = 0; k < 16; k++) {
            uint4 u = wp[k];
            float w0 = bflo(u.x), w1 = bfhi(u.x), w2 = bflo(u.y), w3 = bfhi(u.y);
            float w4 = bflo(u.z), w5 = bfhi(u.z), w6 = bflo(u.w), w7 = bfhi(u.w);
#pragma unroll
            for (int b = 0; b < 8; b++) {
                const float* h8 = hl + b * 128 + k * 8;
                acc[b] += w0 * h8[0] + w1 * h8[1] + w2 * h8[2] + w3 * h8[3]
                        + w4 * h8[4] + w5 * h8[5] + w6 * h8[6] + w7 * h8[7];
            }
        }
    } else {
        const float4* wp = (const float4*)((const float*)Wraw + o * 128);
        for (int k = 0; k < 32; k++) {
            float4 w = wp[k];
#pragma unroll
            for (int b = 0; b < 8; b++) {
                const float* h4 = hl + b * 128 + k * 4;
                acc[b] += w.x * h4[0] + w.y * h4[1] + w.z * h4[2] + w.w * h4[3];
            }
        }
    }
    if (bf) {
        uint16_t* out = (uint16_t*)outv;
#pragma unroll
        for (int b = 0; b < 8; b++) out[(bg * 8 + b) * 18432 + o] = f2bf(acc[b]);
    } else {
        float* out = (float*)outv;
#pragma unroll
        for (int b = 0; b < 8; b++) out[(bg * 8 + b) * 18432 + o] = acc[b];
    }
}

extern "C" void kernel_launch(void* const* d_in, const int* in_sizes, int n_in,
                              void* d_out, int out_size, void* d_ws, size_t ws_size,
                              hipStream_t stream) {
    int E = in_sizes[1] / 2;

    float* ws = (float*)d_ws;
    int* flags = (int*)ws;          // [0]=bf16 [1]=stride [2]=gcount
    float* cWg   = ws + O_WG;
    float* cAtt  = ws + O_AS;
    float* cBias = ws + O_BIAS;
    float* cBih1 = ws + O_BIH1;
    float* cBhh1 = ws + O_BHH1;
    float* cBih2 = ws + O_BIH2;
    float* cBhh2 = ws + O_BHH2;
    float* cBlin = ws + O_BLIN;

    float* base = ws + O_END;
    float* a_s  = base;                            // 524288
    float* a_d  = a_s + 524288;                    // 524288
    int* deg    = (int*)(a_d + 524288);            // 65536
    int* offs   = deg + 65536;                     // 65536
    int* rank   = offs + 65536;                    // E
    int* ssrc   = rank + E;                        // E
    float* gT   = (float*)(ssrc + E);              // 786432
    float* Z1   = gT + 786432;                     // 49152
    float* h2l  = Z1 + 49152;                      // 4096
    float* h1g  = h2l + 4096;                      // 12288  (12*32*32)
    float* z2g  = h1g + 12288;                     // 196608 (12*32*512)
    float* rec  = z2g + 196608;                    // 1048576 (65536 * 16)
    size_t needed = (size_t)((rec + 1048576) - ws) * 4;
    if (ws_size < needed) return;

    k_pre<<<256, 256, 0, stream>>>(d_in[0], (const int*)d_in[1],
                                   d_in[2], d_in[3], d_in[4], d_in[5],
                                   d_in[8], d_in[9], d_in[12], d_in[13], d_in[15],
                                   ws, deg);
    k_nfa<<<2048, 256, 0, stream>>>(d_in[0], cWg, cAtt, flags,
                                    (const int*)d_in[1], E, deg, rank,
                                    a_s, a_d, rec);
    k_scan<<<256, 256, 0, stream>>>(deg, offs, flags + 2);
    k_scatter<<<(E + 255) / 256, 256, 0, stream>>>((const int*)d_in[1], E, flags,
                                                   offs, rank, ssrc);
    k_agg<<<NTOT / 4, 256, 0, stream>>>(d_in[0], cWg, a_s, a_d, offs, deg, ssrc,
                                        cBias, flags, rec, gT);
    k_z1<<<96, 256, 0, stream>>>(gT, d_in[6], cBih1, cBhh1, flags, Z1);
    k_lstm1<<<32, 64, 0, stream>>>(Z1, d_in[7], flags, h1g);
    k_wih2<<<384, 512, 0, stream>>>(h1g, d_in[10], cBih2, cBhh2, flags, z2g);
    k_lstm2<<<32, 512, 0, stream>>>(z2g, d_in[11], flags, h2l);
    k_lin<<<dim3(72, 4), 256, 0, stream>>>(h2l, d_in[14], cBlin, flags, d_out);
}